// Round 1
// baseline (2547.856 us; speedup 1.0000x reference)
//
#include <hip/hip_runtime.h>
#include <hip/hip_bf16.h>
#include <math.h>

// Problem dims (fixed by setup_inputs)
#define BSZ    16
#define DMODEL 1024
#define QLEN   256
#define MLEN   256
#define KLEN   512
#define NHEAD  16
#define DHEAD  64
#define DINNER 4096
#define LOCALW 128   // LOCAL_SIZE

// ---------------- Tiled fp32 GEMM, NN: C[M,N] = A[M,K] * B[K,N] ----------------
// B is "virtual": cols [0,split) from B0 (ld ldb0), cols [split,N) from B1 (ld ldb1).
// Optional epilogue: + E[m*N+n] (per-batch) + bias[m].
#define BM 64
#define BN 64
#define BK 16

__global__ __launch_bounds__(256) void gemm_nn(
    const float* __restrict__ A,
    const float* __restrict__ B0, const float* __restrict__ B1,
    long long b0_stride, long long b1_stride,
    int ldb0, int ldb1,
    float* __restrict__ C, long long c_stride,
    const float* __restrict__ E, long long e_stride,
    const float* __restrict__ bias,
    int M, int N, int K, int split)
{
    int b = blockIdx.z;
    const float* Bp0 = B0 ? B0 + (long long)b * b0_stride : nullptr;
    const float* Bp1 = B1 ? B1 + (long long)b * b1_stride : nullptr;
    float* Cp = C + (long long)b * c_stride;
    const float* Ep = E ? E + (long long)b * e_stride : nullptr;

    __shared__ float As[BK][BM];
    __shared__ float Bs[BK][BN];

    int t  = threadIdx.x;
    int tx = t & 15, ty = t >> 4;
    int m0 = blockIdx.y * BM;
    int n0 = blockIdx.x * BN;

    int am  = t >> 2;          // 0..63
    int ak4 = (t & 3) << 2;    // 0,4,8,12
    int bk  = t >> 4;          // 0..15
    int bn4 = (t & 15) << 2;   // 0..60

    float c[4][4] = {};
    for (int k0 = 0; k0 < K; k0 += BK) {
        float4 av = *(const float4*)&A[(long long)(m0 + am) * K + k0 + ak4];
        As[ak4 + 0][am] = av.x; As[ak4 + 1][am] = av.y;
        As[ak4 + 2][am] = av.z; As[ak4 + 3][am] = av.w;

        int n = n0 + bn4;
        float4 bv;
        if (n < split) bv = *(const float4*)&Bp0[(long long)(k0 + bk) * ldb0 + n];
        else           bv = *(const float4*)&Bp1[(long long)(k0 + bk) * ldb1 + (n - split)];
        *(float4*)&Bs[bk][bn4] = bv;
        __syncthreads();

#pragma unroll
        for (int kk = 0; kk < BK; ++kk) {
            float4 a  = *(const float4*)&As[kk][ty << 2];
            float4 bb = *(const float4*)&Bs[kk][tx << 2];
            float aa[4]  = {a.x, a.y, a.z, a.w};
            float bbv[4] = {bb.x, bb.y, bb.z, bb.w};
#pragma unroll
            for (int u = 0; u < 4; ++u)
#pragma unroll
                for (int v = 0; v < 4; ++v)
                    c[u][v] = fmaf(aa[u], bbv[v], c[u][v]);
        }
        __syncthreads();
    }

#pragma unroll
    for (int u = 0; u < 4; ++u) {
        int m = m0 + (ty << 2) + u;
        int n = n0 + (tx << 2);
        float bm = bias ? bias[m] : 0.f;
        float4 out;
        out.x = c[u][0] + bm; out.y = c[u][1] + bm;
        out.z = c[u][2] + bm; out.w = c[u][3] + bm;
        if (Ep) {
            float4 ev = *(const float4*)&Ep[(long long)m * N + n];
            out.x += ev.x; out.y += ev.y; out.z += ev.z; out.w += ev.w;
        }
        *(float4*)&Cp[(long long)m * N + n] = out;
    }
}

// ---------------- Tiled fp32 GEMM, NT: C[M,N] = A[M,K] * B[N,K]^T ----------------
// Epilogue: + bias[n], optional residual R[M,N], optional ReLU.
__global__ __launch_bounds__(256) void gemm_nt(
    const float* __restrict__ A, const float* __restrict__ B,
    float* __restrict__ C,
    const float* __restrict__ bias, const float* __restrict__ R,
    int M, int N, int K, int relu)
{
    __shared__ float As[BK][BM];
    __shared__ float Bs[BK][BN];

    int t  = threadIdx.x;
    int tx = t & 15, ty = t >> 4;
    int m0 = blockIdx.y * BM;
    int n0 = blockIdx.x * BN;

    int am  = t >> 2;
    int ak4 = (t & 3) << 2;

    float c[4][4] = {};
    for (int k0 = 0; k0 < K; k0 += BK) {
        float4 av = *(const float4*)&A[(long long)(m0 + am) * K + k0 + ak4];
        As[ak4 + 0][am] = av.x; As[ak4 + 1][am] = av.y;
        As[ak4 + 2][am] = av.z; As[ak4 + 3][am] = av.w;
        float4 bv = *(const float4*)&B[(long long)(n0 + am) * K + k0 + ak4];
        Bs[ak4 + 0][am] = bv.x; Bs[ak4 + 1][am] = bv.y;
        Bs[ak4 + 2][am] = bv.z; Bs[ak4 + 3][am] = bv.w;
        __syncthreads();

#pragma unroll
        for (int kk = 0; kk < BK; ++kk) {
            float4 a  = *(const float4*)&As[kk][ty << 2];
            float4 bb = *(const float4*)&Bs[kk][tx << 2];
            float aa[4]  = {a.x, a.y, a.z, a.w};
            float bbv[4] = {bb.x, bb.y, bb.z, bb.w};
#pragma unroll
            for (int u = 0; u < 4; ++u)
#pragma unroll
                for (int v = 0; v < 4; ++v)
                    c[u][v] = fmaf(aa[u], bbv[v], c[u][v]);
        }
        __syncthreads();
    }

#pragma unroll
    for (int u = 0; u < 4; ++u) {
        int m = m0 + (ty << 2) + u;
        int n = n0 + (tx << 2);
        float4 out = {c[u][0], c[u][1], c[u][2], c[u][3]};
        if (bias) {
            float4 bv = *(const float4*)&bias[n];
            out.x += bv.x; out.y += bv.y; out.z += bv.z; out.w += bv.w;
        }
        if (R) {
            float4 rv = *(const float4*)&R[(long long)m * N + n];
            out.x += rv.x; out.y += rv.y; out.z += rv.z; out.w += rv.w;
        }
        if (relu) {
            out.x = fmaxf(out.x, 0.f); out.y = fmaxf(out.y, 0.f);
            out.z = fmaxf(out.z, 0.f); out.w = fmaxf(out.w, 0.f);
        }
        *(float4*)&C[(long long)m * N + n] = out;
    }
}

// ---------------- Windowed rel-pos attention ----------------
// One block per (b, n, i). Unmasked keys: j in [i+129, i+256] (exactly 128).
// BD[i,j] = BD_raw[i, j-i+255] -> window offset t maps to rel col jj = t+384.
__global__ __launch_bounds__(128) void attn_kernel(
    const float* __restrict__ wh,   // [b, 3072, 512] (q rows 0..1023, k 1024.., v 2048..)
    const float* __restrict__ rhk,  // [1024, 512] = [(n*64+d), jj]
    const float* __restrict__ rwb,  // [16,64]
    const float* __restrict__ rrb,  // [16,64]
    float* __restrict__ av)         // [b, 1024, 256]
{
    int i = blockIdx.x;   // query 0..255
    int n = blockIdx.y;   // head
    int b = blockIdx.z;   // batch
    int t = threadIdx.x;  // 0..127

    __shared__ float qw[64], qr[64], prob[128], red[128];

    const float* whb = wh + (long long)b * 3072 * 512;
    if (t < 64) {
        float qv = whb[(long long)(n * 64 + t) * 512 + MLEN + i];
        qw[t] = qv + rwb[n * 64 + t];
        qr[t] = qv + rrb[n * 64 + t];
    }
    __syncthreads();

    int j = i + 129 + t;  // key position, always in [129, 511]
    const float* kcol = whb + (long long)(1024 + n * 64) * 512 + j;
    const float* rcol = rhk + (long long)(n * 64) * 512 + (t + 384);
    float s = 0.f;
#pragma unroll 8
    for (int d = 0; d < 64; ++d)
        s += qw[d] * kcol[(long long)d * 512] + qr[d] * rcol[(long long)d * 512];
    s *= 0.125f;  // 1/sqrt(64)

    red[t] = s;
    __syncthreads();
    for (int off = 64; off > 0; off >>= 1) {
        if (t < off) red[t] = fmaxf(red[t], red[t + off]);
        __syncthreads();
    }
    float mx = red[0];
    __syncthreads();
    float e = expf(s - mx);
    red[t] = e;
    __syncthreads();
    for (int off = 64; off > 0; off >>= 1) {
        if (t < off) red[t] += red[t + off];
        __syncthreads();
    }
    float inv = 1.f / red[0];
    prob[t] = e * inv;
    __syncthreads();

    if (t < 64) {
        const float* vrow = whb + (long long)(2048 + n * 64 + t) * 512 + (i + 129);
        float acc = 0.f;
#pragma unroll 8
        for (int jj = 0; jj < 128; ++jj)
            acc += prob[jj] * vrow[jj];
        av[(long long)b * 1024 * 256 + (long long)(n * 64 + t) * 256 + i] = acc;
    }
}

// ---------------- LayerNorm over d_model, [b,d,q] -> [b,q,d] ----------------
__global__ __launch_bounds__(256) void ln_dq_to_qd(
    const float* __restrict__ X,  // [b, 1024, 256]
    float* __restrict__ H)        // [b, 256, 1024]
{
    int q = blockIdx.x, b = blockIdx.y, t = threadIdx.x;
    __shared__ float r1[256], r2[256];
    const float* xb = X + (long long)b * 1024 * 256 + q;
    float v[4], s = 0.f, ss = 0.f;
#pragma unroll
    for (int u = 0; u < 4; ++u) {
        v[u] = xb[(long long)(t + u * 256) * 256];
        s += v[u]; ss += v[u] * v[u];
    }
    r1[t] = s; r2[t] = ss;
    __syncthreads();
    for (int off = 128; off > 0; off >>= 1) {
        if (t < off) { r1[t] += r1[t + off]; r2[t] += r2[t + off]; }
        __syncthreads();
    }
    float mean = r1[0] * (1.f / 1024.f);
    float var  = r2[0] * (1.f / 1024.f) - mean * mean;
    float rstd = rsqrtf(var + 1e-5f);
    float* hb = H + (long long)b * 256 * 1024 + (long long)q * 1024;
#pragma unroll
    for (int u = 0; u < 4; ++u)
        hb[t + u * 256] = (v[u] - mean) * rstd;
}

// ---------------- LayerNorm over d_model, [bq, d] -> out [b,d,q] ----------------
__global__ __launch_bounds__(256) void ln_qd_to_dq(
    const float* __restrict__ X,  // [b*256, 1024]
    float* __restrict__ O)        // [b, 1024, 256]
{
    int q = blockIdx.x, b = blockIdx.y, t = threadIdx.x;
    __shared__ float r1[256], r2[256];
    const float* xr = X + (long long)(b * 256 + q) * 1024;
    float v[4], s = 0.f, ss = 0.f;
#pragma unroll
    for (int u = 0; u < 4; ++u) {
        v[u] = xr[t + u * 256];
        s += v[u]; ss += v[u] * v[u];
    }
    r1[t] = s; r2[t] = ss;
    __syncthreads();
    for (int off = 128; off > 0; off >>= 1) {
        if (t < off) { r1[t] += r1[t + off]; r2[t] += r2[t + off]; }
        __syncthreads();
    }
    float mean = r1[0] * (1.f / 1024.f);
    float var  = r2[0] * (1.f / 1024.f) - mean * mean;
    float rstd = rsqrtf(var + 1e-5f);
    float* ob = O + (long long)b * 1024 * 256 + q;
#pragma unroll
    for (int u = 0; u < 4; ++u)
        ob[(long long)(t + u * 256) * 256] = (v[u] - mean) * rstd;
}

extern "C" void kernel_launch(void* const* d_in, const int* in_sizes, int n_in,
                              void* d_out, int out_size, void* d_ws, size_t ws_size,
                              hipStream_t stream) {
    const float* z1ss    = (const float*)d_in[0];   // [16,1024,256]
    const float* uss     = (const float*)d_in[1];   // [16,3072,512]
    const float* mems    = (const float*)d_in[2];   // [16,1024,256]
    const float* pos_emb = (const float*)d_in[3];   // [1024,512]
    const float* Wqkv    = (const float*)d_in[4];   // [3072,1024]
    const float* Wr      = (const float*)d_in[5];   // [1024,1024]
    const float* Wo      = (const float*)d_in[6];   // [1024,1024]
    const float* bo      = (const float*)d_in[7];   // [1024]
    const float* rwb     = (const float*)d_in[8];   // [16,64]
    const float* rrb     = (const float*)d_in[9];   // [16,64]
    const float* W1      = (const float*)d_in[10];  // [4096,1024]
    const float* b1      = (const float*)d_in[11];  // [4096]
    const float* W2      = (const float*)d_in[12];  // [1024,4096]
    const float* b2      = (const float*)d_in[13];  // [1024]

    float* ws  = (float*)d_ws;
    float* wh  = ws;                        // [16,3072,512]  = 25165824 floats
    float* rhk = wh + 25165824;             // [1024,512]     = 524288
    float* av  = rhk + 524288;              // [16,1024,256]  = 4194304
    float* at  = av + 4194304;              // [16,1024,256]  = 4194304
    float* h   = at + 4194304;              // [16,256,1024]  = 4194304
    float* ff  = wh;                        // reuse: [4096,4096] = 16777216 (fits)
    float* ff2 = at;                        // reuse: [4096,1024]

    // 1) w_heads = Wqkv @ concat(mems, z1ss) + uss      [b,3072,512]
    gemm_nn<<<dim3(KLEN / BN, 3072 / BM, BSZ), 256, 0, stream>>>(
        Wqkv, mems, z1ss, 1024LL * 256, 1024LL * 256, 256, 256,
        wh, 3072LL * 512, uss, 3072LL * 512, nullptr,
        3072, KLEN, 1024, MLEN);

    // 2) r_head_k = Wr @ pos_emb                        [1024,512]
    gemm_nn<<<dim3(KLEN / BN, 1024 / BM, 1), 256, 0, stream>>>(
        Wr, nullptr, pos_emb, 0, 0, 0, KLEN,
        rhk, 0, nullptr, 0, nullptr,
        1024, KLEN, 1024, 0);

    // 3) windowed attention -> attn_vec                 [b,1024,256]
    attn_kernel<<<dim3(QLEN, NHEAD, BSZ), 128, 0, stream>>>(wh, rhk, rwb, rrb, av);

    // 4) attn_out = Wo @ attn_vec + bo + z1ss           [b,1024,256]
    gemm_nn<<<dim3(QLEN / BN, 1024 / BM, BSZ), 256, 0, stream>>>(
        Wo, nullptr, av, 0, 1024LL * 256, 0, QLEN,
        at, 1024LL * 256, z1ss, 1024LL * 256, bo,
        1024, QLEN, 1024, 0);

    // 5) h = LN(at) transposed to [b,q,d]
    ln_dq_to_qd<<<dim3(QLEN, BSZ), 256, 0, stream>>>(at, h);

    // 6) ff = relu(h @ W1^T + b1)                       [4096,4096]
    gemm_nt<<<dim3(DINNER / BN, (BSZ * QLEN) / BM), 256, 0, stream>>>(
        h, W1, ff, b1, nullptr, BSZ * QLEN, DINNER, 1024, 1);

    // 7) ff2 = ff @ W2^T + b2 + h                       [4096,1024]
    gemm_nt<<<dim3(1024 / BN, (BSZ * QLEN) / BM), 256, 0, stream>>>(
        ff, W2, ff2, b2, h, BSZ * QLEN, 1024, DINNER, 0);

    // 8) out = LN(ff2) transposed to [b,d,q]
    ln_qd_to_dq<<<dim3(QLEN, BSZ), 256, 0, stream>>>(ff2, (float*)d_out);
}

// Round 2
// 1239.645 us; speedup vs baseline: 2.0553x; 2.0553x over previous
//
#include <hip/hip_runtime.h>
#include <hip/hip_bf16.h>
#include <math.h>

// Problem dims (fixed by setup_inputs)
#define BSZ    16
#define DMODEL 1024
#define QLEN   256
#define MLEN   256
#define KLEN   512
#define NHEAD  16
#define DHEAD  64
#define DINNER 4096

typedef __bf16 bf16;
typedef bf16 bf16x8 __attribute__((ext_vector_type(8)));
typedef float f32x4 __attribute__((ext_vector_type(4)));

#define GLOBAL_AS __attribute__((address_space(1)))
#define LDS_AS    __attribute__((address_space(3)))

// ---------------- fp32 -> bf16 straight cast (n must be /4) ----------------
__global__ __launch_bounds__(256) void cast_bf16_k(
    const float* __restrict__ in, bf16* __restrict__ out, int n4)
{
    int i = blockIdx.x * 256 + threadIdx.x;
    if (i < n4) {
        float4 v = ((const float4*)in)[i];
        bf16 b0 = (bf16)v.x, b1 = (bf16)v.y, b2 = (bf16)v.z, b3 = (bf16)v.w;
        union { ushort u[4]; uint2 d; } p;
        p.u[0] = *(ushort*)&b0; p.u[1] = *(ushort*)&b1;
        p.u[2] = *(ushort*)&b2; p.u[3] = *(ushort*)&b3;
        ((uint2*)out)[i] = p.d;
    }
}

// ---------------- fp32 [R,C] -> bf16 [C,R] transpose-cast ----------------
__global__ __launch_bounds__(256) void transpose_cast_k(
    const float* __restrict__ in, long long inBatch, int ldi,
    bf16* __restrict__ out, long long outBatch, int ldo)
{
    __shared__ float tile[32][33];
    int b = blockIdx.z;
    const float* ip = in + (long long)b * inBatch;
    bf16* op = out + (long long)b * outBatch;
    int tx = threadIdx.x & 31, ty = threadIdx.x >> 5;  // 32 x 8
    int r0 = blockIdx.y * 32, c0 = blockIdx.x * 32;
#pragma unroll
    for (int yy = ty; yy < 32; yy += 8)
        tile[yy][tx] = ip[(long long)(r0 + yy) * ldi + c0 + tx];
    __syncthreads();
#pragma unroll
    for (int yy = ty; yy < 32; yy += 8)
        op[(long long)(c0 + yy) * ldo + r0 + tx] = (bf16)tile[tx][yy];
}

// ---------------- bf16 MFMA GEMM: C[M,N] = A[M,K] * B[N,K]^T ----------------
// 128x128 tile, BK=32, 4 waves (2x2), 16x16x32 MFMA, global_load_lds staging.
// Epilogue: +bias[n]; emode 1: +E[m*ldE+n] (fp32, per-batch); emode 2:
// +E[((m>>8)*1024+n)*256+(m&255)] (z1ss-transposed residual); relu; outF/outB.
__global__ __launch_bounds__(256) void gemm_bf16(
    const bf16* __restrict__ A, long long aBatch,
    const bf16* __restrict__ B, long long bBatch,
    int M, int N, int K,
    const float* __restrict__ bias,
    const float* __restrict__ E, long long eBatch, int ldE, int emode,
    int relu,
    float* __restrict__ outF, long long ofBatch,
    bf16* __restrict__ outB, long long obBatch)
{
    __shared__ bf16 lA[128 * 32];
    __shared__ bf16 lB[128 * 32];

    int t = threadIdx.x;
    int w = t >> 6, lane = t & 63;
    int m0 = blockIdx.y * 128, n0 = blockIdx.x * 128;
    int bz = blockIdx.z;
    const bf16* Ap = A + (long long)bz * aBatch;
    const bf16* Bp = B + (long long)bz * bBatch;

    int q = lane >> 4, r16 = lane & 15;
    int wm = w >> 1, wn = w & 1;

    f32x4 acc[4][4];
#pragma unroll
    for (int i = 0; i < 4; ++i)
#pragma unroll
        for (int j = 0; j < 4; ++j)
            acc[i][j] = (f32x4){0.f, 0.f, 0.f, 0.f};

    int srow = (lane >> 2);        // row within 16-row chunk
    int scol = (lane & 3) * 8;     // element col within 32

    for (int k0 = 0; k0 < K; k0 += 32) {
        __syncthreads();
#pragma unroll
        for (int issue = 0; issue < 2; ++issue) {
            int c = issue * 4 + w;           // chunk 0..7 (16 rows each)
            int row = c * 16 + srow;
            __builtin_amdgcn_global_load_lds(
                (const GLOBAL_AS void*)(Ap + (long long)(m0 + row) * K + k0 + scol),
                (LDS_AS void*)(lA + c * 512 + lane * 8), 16, 0, 0);
            __builtin_amdgcn_global_load_lds(
                (const GLOBAL_AS void*)(Bp + (long long)(n0 + row) * K + k0 + scol),
                (LDS_AS void*)(lB + c * 512 + lane * 8), 16, 0, 0);
        }
        __syncthreads();  // compiler emits vmcnt(0) drain before barrier

        bf16x8 af[4], bfr[4];
#pragma unroll
        for (int i = 0; i < 4; ++i)
            af[i] = *(const bf16x8*)&lA[(wm * 64 + i * 16 + r16) * 32 + q * 8];
#pragma unroll
        for (int j = 0; j < 4; ++j)
            bfr[j] = *(const bf16x8*)&lB[(wn * 64 + j * 16 + r16) * 32 + q * 8];
#pragma unroll
        for (int i = 0; i < 4; ++i)
#pragma unroll
            for (int j = 0; j < 4; ++j)
                acc[i][j] = __builtin_amdgcn_mfma_f32_16x16x32_bf16(
                    af[i], bfr[j], acc[i][j], 0, 0, 0);
    }

    const float* Ep = E ? E + (long long)bz * eBatch : nullptr;
    float* oF = outF ? outF + (long long)bz * ofBatch : nullptr;
    bf16*  oB = outB ? outB + (long long)bz * obBatch : nullptr;

#pragma unroll
    for (int i = 0; i < 4; ++i) {
#pragma unroll
        for (int r = 0; r < 4; ++r) {
            int m = m0 + wm * 64 + i * 16 + q * 4 + r;
#pragma unroll
            for (int j = 0; j < 4; ++j) {
                int n = n0 + wn * 64 + j * 16 + r16;
                float v = acc[i][j][r];
                if (bias) v += bias[n];
                if (emode == 1)      v += Ep[(long long)m * ldE + n];
                else if (emode == 2) v += Ep[((long long)(m >> 8) * 1024 + n) * 256 + (m & 255)];
                if (relu) v = fmaxf(v, 0.f);
                if (oF) oF[(long long)m * N + n] = v;
                if (oB) oB[(long long)m * N + n] = (bf16)v;
            }
        }
    }
}

// ---------------- Windowed rel-pos attention ----------------
// One block per (b, n, i). Unmasked keys: j in [i+129, i+256] (exactly 128).
// BD[i,j] = BD_raw[i, j-i+255] -> window offset t maps to rel col jj = t+384.
__global__ __launch_bounds__(128) void attn_kernel(
    const float* __restrict__ qc,   // [b,1024,256]
    const float* __restrict__ kv,   // [b,2048,512] rows 0..1023 = k, 1024..2047 = v
    const bf16*  __restrict__ rhk,  // [1024,512]
    const float* __restrict__ rwb,  // [16,64]
    const float* __restrict__ rrb,  // [16,64]
    bf16* __restrict__ avT)         // [(b*256+i)*1024 + n*64+d]
{
    int i = blockIdx.x;   // query 0..255
    int n = blockIdx.y;   // head
    int b = blockIdx.z;   // batch
    int t = threadIdx.x;  // 0..127

    __shared__ float qw[64], qr[64], prob[128], red[128];

    if (t < 64) {
        float qv = qc[((long long)b * 1024 + n * 64 + t) * 256 + i];
        qw[t] = qv + rwb[n * 64 + t];
        qr[t] = qv + rrb[n * 64 + t];
    }
    __syncthreads();

    int j = i + 129 + t;  // key position in [129, 511]
    const float* kcol = kv + (long long)b * 2048 * 512 + (long long)(n * 64) * 512 + j;
    const bf16*  rcol = rhk + (long long)(n * 64) * 512 + (t + 384);
    float s = 0.f;
#pragma unroll 8
    for (int d = 0; d < 64; ++d)
        s += qw[d] * kcol[(long long)d * 512] + qr[d] * (float)rcol[(long long)d * 512];
    s *= 0.125f;  // 1/sqrt(64)

    red[t] = s;
    __syncthreads();
    for (int off = 64; off > 0; off >>= 1) {
        if (t < off) red[t] = fmaxf(red[t], red[t + off]);
        __syncthreads();
    }
    float mx = red[0];
    __syncthreads();
    float e = expf(s - mx);
    red[t] = e;
    __syncthreads();
    for (int off = 64; off > 0; off >>= 1) {
        if (t < off) red[t] += red[t + off];
        __syncthreads();
    }
    float inv = 1.f / red[0];
    prob[t] = e * inv;
    __syncthreads();

    if (t < 64) {
        const float* vrow = kv + (long long)b * 2048 * 512 + (long long)(1024 + n * 64 + t) * 512 + (i + 129);
        float acc = 0.f;
#pragma unroll 8
        for (int jj = 0; jj < 128; ++jj)
            acc += prob[jj] * vrow[jj];
        avT[((long long)b * 256 + i) * 1024 + n * 64 + t] = (bf16)acc;
    }
}

// ---------------- LayerNorm rows of [4096,1024] -> bf16 ----------------
__global__ __launch_bounds__(256) void ln_bf16_k(
    const float* __restrict__ X, bf16* __restrict__ H)
{
    int row = blockIdx.x, t = threadIdx.x;
    __shared__ float r1[256], r2[256];
    const float* xr = X + (long long)row * 1024;
    float v[4], s = 0.f, ss = 0.f;
#pragma unroll
    for (int u = 0; u < 4; ++u) {
        v[u] = xr[t + u * 256];
        s += v[u]; ss += v[u] * v[u];
    }
    r1[t] = s; r2[t] = ss;
    __syncthreads();
    for (int off = 128; off > 0; off >>= 1) {
        if (t < off) { r1[t] += r1[t + off]; r2[t] += r2[t + off]; }
        __syncthreads();
    }
    float mean = r1[0] * (1.f / 1024.f);
    float var  = r2[0] * (1.f / 1024.f) - mean * mean;
    float rstd = rsqrtf(var + 1e-5f);
    bf16* hr = H + (long long)row * 1024;
#pragma unroll
    for (int u = 0; u < 4; ++u)
        hr[t + u * 256] = (bf16)((v[u] - mean) * rstd);
}

// ---------------- Final: h=LN(x1); y=x2+h; out=LN(y) transposed ----------------
__global__ __launch_bounds__(256) void ln_final_k(
    const float* __restrict__ X1,   // [4096,1024] pre-LN attn output
    const float* __restrict__ X2,   // [4096,1024] W2@ff + b2 (no residual yet)
    float* __restrict__ O)          // [b,1024,256]
{
    int row = blockIdx.x, t = threadIdx.x;
    int b = row >> 8, qq = row & 255;
    __shared__ float r1[256], r2[256];
    const float* x1 = X1 + (long long)row * 1024;
    const float* x2 = X2 + (long long)row * 1024;

    float v1[4], s = 0.f, ss = 0.f;
#pragma unroll
    for (int u = 0; u < 4; ++u) {
        v1[u] = x1[t + u * 256];
        s += v1[u]; ss += v1[u] * v1[u];
    }
    r1[t] = s; r2[t] = ss;
    __syncthreads();
    for (int off = 128; off > 0; off >>= 1) {
        if (t < off) { r1[t] += r1[t + off]; r2[t] += r2[t + off]; }
        __syncthreads();
    }
    float mean = r1[0] * (1.f / 1024.f);
    float var  = r2[0] * (1.f / 1024.f) - mean * mean;
    float rstd = rsqrtf(var + 1e-5f);
    __syncthreads();

    float y[4]; s = 0.f; ss = 0.f;
#pragma unroll
    for (int u = 0; u < 4; ++u) {
        y[u] = x2[t + u * 256] + (v1[u] - mean) * rstd;
        s += y[u]; ss += y[u] * y[u];
    }
    r1[t] = s; r2[t] = ss;
    __syncthreads();
    for (int off = 128; off > 0; off >>= 1) {
        if (t < off) { r1[t] += r1[t + off]; r2[t] += r2[t + off]; }
        __syncthreads();
    }
    float mean2 = r1[0] * (1.f / 1024.f);
    float var2  = r2[0] * (1.f / 1024.f) - mean2 * mean2;
    float rstd2 = rsqrtf(var2 + 1e-5f);

    float* ob = O + (long long)b * 1024 * 256 + qq;
#pragma unroll
    for (int u = 0; u < 4; ++u)
        ob[(long long)(t + u * 256) * 256] = (y[u] - mean2) * rstd2;
}

extern "C" void kernel_launch(void* const* d_in, const int* in_sizes, int n_in,
                              void* d_out, int out_size, void* d_ws, size_t ws_size,
                              hipStream_t stream) {
    const float* z1ss    = (const float*)d_in[0];   // [16,1024,256]
    const float* uss     = (const float*)d_in[1];   // [16,3072,512]
    const float* mems    = (const float*)d_in[2];   // [16,1024,256]
    const float* pos_emb = (const float*)d_in[3];   // [1024,512]
    const float* Wqkv    = (const float*)d_in[4];   // [3072,1024]
    const float* Wr      = (const float*)d_in[5];   // [1024,1024]
    const float* Wo      = (const float*)d_in[6];   // [1024,1024]
    const float* bo      = (const float*)d_in[7];   // [1024]
    const float* rwb     = (const float*)d_in[8];   // [16,64]
    const float* rrb     = (const float*)d_in[9];   // [16,64]
    const float* W1      = (const float*)d_in[10];  // [4096,1024]
    const float* b1      = (const float*)d_in[11];  // [4096]
    const float* W2      = (const float*)d_in[12];  // [1024,4096]
    const float* b2      = (const float*)d_in[13];  // [1024]

    char* base = (char*)d_ws;
    // region map (bytes); total 146,800,640 <= round-0's 153 MB footprint
    float* kv    = (float*)(base + 0);               // [16,2048,512] fp32 (67.1 MB)
    bf16*  ff_b  = (bf16*) (base + 0);               // reuse after attn: [4096,4096] bf16
    float* x2    = (float*)(base + 33554432);        // reuse after attn: [4096,1024] fp32
    float* qc    = (float*)(base + 67108864);        // [16,1024,256] fp32
    bf16*  catT  = (bf16*) (base + 83886080);        // [16,512,1024] bf16
    float* x1    = (float*)(base + 83886080);        // reuse after w_heads: [4096,1024] fp32
    bf16*  posT  = (bf16*) (base + 100663296);       // [512,1024]
    bf16*  rhkB  = (bf16*) (base + 101711872);       // [1024,512]
    bf16*  WqkvB = (bf16*) (base + 102760448);       // [3072,1024]
    bf16*  WrB   = (bf16*) (base + 109051904);       // [1024,1024]
    bf16*  WoB   = (bf16*) (base + 111149056);       // [1024,1024]
    bf16*  W1B   = (bf16*) (base + 113246208);       // [4096,1024]
    bf16*  W2B   = (bf16*) (base + 121634816);       // [1024,4096]
    bf16*  avTB  = (bf16*) (base + 130023424);       // [4096,1024]
    bf16*  hB    = (bf16*) (base + 138412032);       // [4096,1024]

    // ---- weight casts ----
    cast_bf16_k<<<(3072 * 1024 / 4 + 255) / 256, 256, 0, stream>>>(Wqkv, WqkvB, 3072 * 1024 / 4);
    cast_bf16_k<<<(1024 * 1024 / 4 + 255) / 256, 256, 0, stream>>>(Wr, WrB, 1024 * 1024 / 4);
    cast_bf16_k<<<(1024 * 1024 / 4 + 255) / 256, 256, 0, stream>>>(Wo, WoB, 1024 * 1024 / 4);
    cast_bf16_k<<<(4096 * 1024 / 4 + 255) / 256, 256, 0, stream>>>(W1, W1B, 4096 * 1024 / 4);
    cast_bf16_k<<<(4096 * 1024 / 4 + 255) / 256, 256, 0, stream>>>(W2, W2B, 4096 * 1024 / 4);

    // ---- transposed bf16 activations: catT rows 0..255 = memsT, 256..511 = z1ssT ----
    transpose_cast_k<<<dim3(256 / 32, 1024 / 32, BSZ), 256, 0, stream>>>(
        mems, 1024LL * 256, 256, catT, 512LL * 1024, 1024);
    transpose_cast_k<<<dim3(256 / 32, 1024 / 32, BSZ), 256, 0, stream>>>(
        z1ss, 1024LL * 256, 256, catT + 256 * 1024, 512LL * 1024, 1024);
    transpose_cast_k<<<dim3(512 / 32, 1024 / 32, 1), 256, 0, stream>>>(
        pos_emb, 0, 512, posT, 0, 1024);

    // ---- w_heads q-part: q[b,1024,256] = Wqkv[0:1024] @ cat(:, 256:) + uss ----
    gemm_bf16<<<dim3(2, 8, BSZ), 256, 0, stream>>>(
        WqkvB, 0, catT + 256 * 1024, 512LL * 1024,
        1024, 256, 1024,
        nullptr, uss + 256, 3072LL * 512, 512, 1, 0,
        qc, 1024LL * 256, nullptr, 0);

    // ---- w_heads k/v: kv[b,2048,512] = Wqkv[1024:3072] @ cat + uss ----
    gemm_bf16<<<dim3(4, 16, BSZ), 256, 0, stream>>>(
        WqkvB + 1024 * 1024, 0, catT, 512LL * 1024,
        2048, 512, 1024,
        nullptr, uss + 1024 * 512, 3072LL * 512, 512, 1, 0,
        kv, 2048LL * 512, nullptr, 0);

    // ---- r_head_k (bf16 out) ----
    gemm_bf16<<<dim3(4, 8, 1), 256, 0, stream>>>(
        WrB, 0, posT, 0,
        1024, 512, 1024,
        nullptr, nullptr, 0, 0, 0, 0,
        nullptr, 0, rhkB, 0);

    // ---- windowed attention -> avT bf16 [bq, nd] ----
    attn_kernel<<<dim3(QLEN, NHEAD, BSZ), 128, 0, stream>>>(qc, kv, rhkB, rwb, rrb, avTB);

    // ---- x1[bq,1024] = avT @ Wo^T + bo + z1ss^T ----
    gemm_bf16<<<dim3(8, 32, 1), 256, 0, stream>>>(
        avTB, 0, WoB, 0,
        4096, 1024, 1024,
        bo, z1ss, 0, 0, 2, 0,
        x1, 0, nullptr, 0);

    // ---- h = LN(x1) -> bf16 ----
    ln_bf16_k<<<4096, 256, 0, stream>>>(x1, hB);

    // ---- ff = relu(h @ W1^T + b1) -> bf16 ----
    gemm_bf16<<<dim3(32, 32, 1), 256, 0, stream>>>(
        hB, 0, W1B, 0,
        4096, 4096, 1024,
        b1, nullptr, 0, 0, 0, 1,
        nullptr, 0, ff_b, 0);

    // ---- x2 = ff @ W2^T + b2 (residual h added in final kernel) ----
    gemm_bf16<<<dim3(8, 32, 1), 256, 0, stream>>>(
        ff_b, 0, W2B, 0,
        4096, 1024, 4096,
        b2, nullptr, 0, 0, 0, 0,
        x2, 0, nullptr, 0);

    // ---- out = LN(x2 + LN(x1)) transposed to [b,d,q] ----
    ln_final_k<<<4096, 256, 0, stream>>>(x1, x2, (float*)d_out);
}

// Round 3
// 769.388 us; speedup vs baseline: 3.3115x; 1.6112x over previous
//
#include <hip/hip_runtime.h>
#include <hip/hip_bf16.h>
#include <math.h>

// Problem dims (fixed by setup_inputs)
#define BSZ    16
#define DMODEL 1024
#define QLEN   256
#define MLEN   256
#define KLEN   512
#define NHEAD  16
#define DHEAD  64
#define DINNER 4096

typedef __bf16 bf16;
typedef bf16 bf16x8 __attribute__((ext_vector_type(8)));
typedef float f32x4 __attribute__((ext_vector_type(4)));

#define GLOBAL_AS __attribute__((address_space(1)))
#define LDS_AS    __attribute__((address_space(3)))

// ---------------- fp32 -> bf16 straight cast (n must be /4) ----------------
__global__ __launch_bounds__(256) void cast_bf16_k(
    const float* __restrict__ in, bf16* __restrict__ out, int n4)
{
    int i = blockIdx.x * 256 + threadIdx.x;
    if (i < n4) {
        float4 v = ((const float4*)in)[i];
        bf16 b0 = (bf16)v.x, b1 = (bf16)v.y, b2 = (bf16)v.z, b3 = (bf16)v.w;
        union { ushort u[4]; uint2 d; } p;
        p.u[0] = *(ushort*)&b0; p.u[1] = *(ushort*)&b1;
        p.u[2] = *(ushort*)&b2; p.u[3] = *(ushort*)&b3;
        ((uint2*)out)[i] = p.d;
    }
}

// ---------------- fp32 [R,C] -> bf16 [C,R] transpose-cast ----------------
__global__ __launch_bounds__(256) void transpose_cast_k(
    const float* __restrict__ in, long long inBatch, int ldi,
    bf16* __restrict__ out, long long outBatch, int ldo)
{
    __shared__ float tile[32][33];
    int b = blockIdx.z;
    const float* ip = in + (long long)b * inBatch;
    bf16* op = out + (long long)b * outBatch;
    int tx = threadIdx.x & 31, ty = threadIdx.x >> 5;  // 32 x 8
    int r0 = blockIdx.y * 32, c0 = blockIdx.x * 32;
#pragma unroll
    for (int yy = ty; yy < 32; yy += 8)
        tile[yy][tx] = ip[(long long)(r0 + yy) * ldi + c0 + tx];
    __syncthreads();
#pragma unroll
    for (int yy = ty; yy < 32; yy += 8)
        op[(long long)(c0 + yy) * ldo + r0 + tx] = (bf16)tile[tx][yy];
}

// ---------------- bf16 MFMA GEMM: C[M,N] = A[M,K] * B[N,K]^T ----------------
// 128x128 tile, BK=32, 4 waves (2x2), 16x16x32 MFMA, global_load_lds staging.
// emode 1: +E[m*ldE+n] (per-batch fp32); emode 2: z1ss-transposed residual
// +E[((m>>8)*1024+n)*256+(m&255)]; emode 3: +E[n*ldE + m + eOff] (uss^T).
__global__ __launch_bounds__(256) void gemm_bf16(
    const bf16* __restrict__ A, long long aBatch,
    const bf16* __restrict__ B, long long bBatch,
    int M, int N, int K,
    const float* __restrict__ bias,
    const float* __restrict__ E, long long eBatch, int ldE, int eOff, int emode,
    int relu,
    float* __restrict__ outF, long long ofBatch,
    bf16* __restrict__ outB, long long obBatch)
{
    __shared__ bf16 lA[128 * 32];
    __shared__ bf16 lB[128 * 32];

    int t = threadIdx.x;
    int w = t >> 6, lane = t & 63;
    int m0 = blockIdx.y * 128, n0 = blockIdx.x * 128;
    int bz = blockIdx.z;
    const bf16* Ap = A + (long long)bz * aBatch;
    const bf16* Bp = B + (long long)bz * bBatch;

    int q = lane >> 4, r16 = lane & 15;
    int wm = w >> 1, wn = w & 1;

    f32x4 acc[4][4];
#pragma unroll
    for (int i = 0; i < 4; ++i)
#pragma unroll
        for (int j = 0; j < 4; ++j)
            acc[i][j] = (f32x4){0.f, 0.f, 0.f, 0.f};

    int srow = (lane >> 2);        // row within 16-row chunk
    int scol = (lane & 3) * 8;     // element col within 32

    for (int k0 = 0; k0 < K; k0 += 32) {
        __syncthreads();
#pragma unroll
        for (int issue = 0; issue < 2; ++issue) {
            int c = issue * 4 + w;           // chunk 0..7 (16 rows each)
            int row = c * 16 + srow;
            __builtin_amdgcn_global_load_lds(
                (const GLOBAL_AS void*)(Ap + (long long)(m0 + row) * K + k0 + scol),
                (LDS_AS void*)(lA + c * 512 + lane * 8), 16, 0, 0);
            __builtin_amdgcn_global_load_lds(
                (const GLOBAL_AS void*)(Bp + (long long)(n0 + row) * K + k0 + scol),
                (LDS_AS void*)(lB + c * 512 + lane * 8), 16, 0, 0);
        }
        __syncthreads();

        bf16x8 af[4], bfr[4];
#pragma unroll
        for (int i = 0; i < 4; ++i)
            af[i] = *(const bf16x8*)&lA[(wm * 64 + i * 16 + r16) * 32 + q * 8];
#pragma unroll
        for (int j = 0; j < 4; ++j)
            bfr[j] = *(const bf16x8*)&lB[(wn * 64 + j * 16 + r16) * 32 + q * 8];
#pragma unroll
        for (int i = 0; i < 4; ++i)
#pragma unroll
            for (int j = 0; j < 4; ++j)
                acc[i][j] = __builtin_amdgcn_mfma_f32_16x16x32_bf16(
                    af[i], bfr[j], acc[i][j], 0, 0, 0);
    }

    const float* Ep = E ? E + (long long)bz * eBatch : nullptr;
    float* oF = outF ? outF + (long long)bz * ofBatch : nullptr;
    bf16*  oB = outB ? outB + (long long)bz * obBatch : nullptr;

#pragma unroll
    for (int i = 0; i < 4; ++i) {
#pragma unroll
        for (int r = 0; r < 4; ++r) {
            int m = m0 + wm * 64 + i * 16 + q * 4 + r;
#pragma unroll
            for (int j = 0; j < 4; ++j) {
                int n = n0 + wn * 64 + j * 16 + r16;
                float v = acc[i][j][r];
                if (bias) v += bias[n];
                if (emode == 1)      v += Ep[(long long)m * ldE + n];
                else if (emode == 2) v += Ep[((long long)(m >> 8) * 1024 + n) * 256 + (m & 255)];
                else if (emode == 3) v += Ep[(long long)n * ldE + m + eOff];
                if (relu) v = fmaxf(v, 0.f);
                if (oF) oF[(long long)m * N + n] = v;
                if (oB) oB[(long long)m * N + n] = (bf16)v;
            }
        }
    }
}

// ---------------- MFMA banded-window rel-pos attention ----------------
// One block per (b, n, i0-tile of 64 queries). 4 waves; wave w owns rows
// [16w, 16w+16). Keys for query i: j in [i+129, i+256] (exactly 128).
// Window for the tile: j in [i0+129, i0+320) -> 192 cols (col 191 never valid).
// S[m][jj] = AC[m][jj] + BD[m][jj-m]; BD col t -> rhkT row 384+t.
__global__ __launch_bounds__(256) void attn_mfma_k(
    const bf16* __restrict__ qT,    // [b,256,1024]
    const bf16* __restrict__ kT,    // [b,512,1024]
    const bf16* __restrict__ vB,    // [b,1024,512]
    const bf16* __restrict__ rhkT,  // [512,1024]
    const float* __restrict__ rwb,  // [16,64]
    const float* __restrict__ rrb,  // [16,64]
    bf16* __restrict__ avT)         // [(b*256+i)*1024 + n*64+d]
{
    // BD rows fp32 stride 132 (528 B); same rows reused as bf16 P, stride 264.
    // Row slots are wave-private (rows partition by wave) -> no cross-wave race.
    __shared__ float sBD[64][132];

    int t = threadIdx.x;
    int w = t >> 6, lane = t & 63;
    int lo = lane & 15, hi = lane >> 4;
    int i0 = blockIdx.x * 64;
    int n  = blockIdx.y;
    int b  = blockIdx.z;

    // ---- q fragments (A-layout: row=lo, kgroup=hi) for rows i0+16w+lo ----
    const bf16* qp = qT + ((long long)(b * 256 + i0 + 16 * w + lo)) * 1024 + n * 64;
    bf16x8 qw[2], qr[2];
#pragma unroll
    for (int ks = 0; ks < 2; ++ks) {
        bf16x8 qv = *(const bf16x8*)(qp + ks * 32 + hi * 8);
        const float* wb = rwb + n * 64 + ks * 32 + hi * 8;
        const float* rb = rrb + n * 64 + ks * 32 + hi * 8;
#pragma unroll
        for (int e = 0; e < 8; ++e) {
            float qf = (float)qv[e];
            qw[ks][e] = (bf16)(qf + wb[e]);
            qr[ks][e] = (bf16)(qf + rb[e]);
        }
    }

    // ---- BD = qr @ rhkT[384+t,:]^T  (rows 16w..16w+16, t in [0,128)) ----
    const bf16* rp = rhkT + (long long)384 * 1024 + n * 64;
#pragma unroll
    for (int tj = 0; tj < 8; ++tj) {
        const bf16* bp = rp + (long long)(16 * tj + lo) * 1024;
        f32x4 a = (f32x4){0.f, 0.f, 0.f, 0.f};
        a = __builtin_amdgcn_mfma_f32_16x16x32_bf16(qr[0], *(const bf16x8*)(bp + hi * 8), a, 0, 0, 0);
        a = __builtin_amdgcn_mfma_f32_16x16x32_bf16(qr[1], *(const bf16x8*)(bp + 32 + hi * 8), a, 0, 0, 0);
#pragma unroll
        for (int r = 0; r < 4; ++r)
            sBD[16 * w + hi * 4 + r][16 * tj + lo] = a[r];
    }
    __syncthreads();

    // ---- AC = qw @ kT[i0+129+jj,:]^T  (12 col-tiles = 192 cols) ----
    f32x4 ac[12];
    const bf16* kp = kT + ((long long)b * 512 + i0 + 129) * 1024 + n * 64;
#pragma unroll
    for (int tj = 0; tj < 12; ++tj) {
        const bf16* bp = kp + (long long)(16 * tj + lo) * 1024;
        f32x4 a = (f32x4){0.f, 0.f, 0.f, 0.f};
        a = __builtin_amdgcn_mfma_f32_16x16x32_bf16(qw[0], *(const bf16x8*)(bp + hi * 8), a, 0, 0, 0);
        a = __builtin_amdgcn_mfma_f32_16x16x32_bf16(qw[1], *(const bf16x8*)(bp + 32 + hi * 8), a, 0, 0, 0);
        ac[tj] = a;
    }

    // ---- band add + in-register softmax (rows m = 16w + hi*4 + r) ----
    float p[12][4], rowmax[4], rowsum[4];
#pragma unroll
    for (int r = 0; r < 4; ++r) rowmax[r] = -1e30f;
#pragma unroll
    for (int tj = 0; tj < 12; ++tj) {
#pragma unroll
        for (int r = 0; r < 4; ++r) {
            int m = 16 * w + hi * 4 + r;
            int jj = 16 * tj + lo;
            int tt = jj - m;
            float v = (tt >= 0 && tt < 128) ? (ac[tj][r] + sBD[m][tt]) * 0.125f
                                            : -1e30f;
            p[tj][r] = v;
            rowmax[r] = fmaxf(rowmax[r], v);
        }
    }
#pragma unroll
    for (int r = 0; r < 4; ++r) {
        float mx = rowmax[r];
#pragma unroll
        for (int msk = 1; msk < 16; msk <<= 1)
            mx = fmaxf(mx, __shfl_xor(mx, msk, 64));
        rowmax[r] = mx;
        rowsum[r] = 0.f;
    }
#pragma unroll
    for (int tj = 0; tj < 12; ++tj) {
#pragma unroll
        for (int r = 0; r < 4; ++r) {
            float e = exp2f((p[tj][r] - rowmax[r]) * 1.44269504f);
            p[tj][r] = e;
            rowsum[r] += e;
        }
    }
#pragma unroll
    for (int r = 0; r < 4; ++r) {
        float s = rowsum[r];
#pragma unroll
        for (int msk = 1; msk < 16; msk <<= 1)
            s += __shfl_xor(s, msk, 64);
        rowsum[r] = 1.f / s;
    }

    // ---- write P (bf16) to LDS (invalid cols get exactly 0) ----
    bf16* P = (bf16*)&sBD[0][0];
#pragma unroll
    for (int tj = 0; tj < 12; ++tj) {
#pragma unroll
        for (int r = 0; r < 4; ++r) {
            int m = 16 * w + hi * 4 + r;
            P[m * 264 + 16 * tj + lo] = (bf16)(p[tj][r] * rowsum[r]);
        }
    }
    __syncthreads();

    // ---- PV: out[m][d] = P[m][:] @ v[d][:]^T  (K=192, V in natural [d,j]) ----
    f32x4 oacc[4];
#pragma unroll
    for (int td = 0; td < 4; ++td) oacc[td] = (f32x4){0.f, 0.f, 0.f, 0.f};
    const bf16* vp = vB + ((long long)b * 1024 + n * 64) * 512 + i0 + 129;
#pragma unroll
    for (int ks = 0; ks < 6; ++ks) {
        bf16x8 af = *(const bf16x8*)(P + (16 * w + lo) * 264 + ks * 32 + hi * 8);
#pragma unroll
        for (int td = 0; td < 4; ++td) {
            bf16x8 bv = *(const bf16x8*)(vp + (long long)(16 * td + lo) * 512 + ks * 32 + hi * 8);
            oacc[td] = __builtin_amdgcn_mfma_f32_16x16x32_bf16(af, bv, oacc[td], 0, 0, 0);
        }
    }
    bf16* op = avT + ((long long)(b * 256 + i0 + 16 * w)) * 1024 + n * 64;
#pragma unroll
    for (int td = 0; td < 4; ++td)
#pragma unroll
        for (int r = 0; r < 4; ++r)
            op[(long long)(hi * 4 + r) * 1024 + 16 * td + lo] = (bf16)oacc[td][r];
}

// ---------------- LayerNorm rows of [4096,1024] -> bf16 ----------------
__global__ __launch_bounds__(256) void ln_bf16_k(
    const float* __restrict__ X, bf16* __restrict__ H)
{
    int row = blockIdx.x, t = threadIdx.x;
    __shared__ float r1[256], r2[256];
    const float* xr = X + (long long)row * 1024;
    float v[4], s = 0.f, ss = 0.f;
#pragma unroll
    for (int u = 0; u < 4; ++u) {
        v[u] = xr[t + u * 256];
        s += v[u]; ss += v[u] * v[u];
    }
    r1[t] = s; r2[t] = ss;
    __syncthreads();
    for (int off = 128; off > 0; off >>= 1) {
        if (t < off) { r1[t] += r1[t + off]; r2[t] += r2[t + off]; }
        __syncthreads();
    }
    float mean = r1[0] * (1.f / 1024.f);
    float var  = r2[0] * (1.f / 1024.f) - mean * mean;
    float rstd = rsqrtf(var + 1e-5f);
    bf16* hr = H + (long long)row * 1024;
#pragma unroll
    for (int u = 0; u < 4; ++u)
        hr[t + u * 256] = (bf16)((v[u] - mean) * rstd);
}

// ---------------- Final: h=LN(x1); y=x2+h; out=LN(y) transposed ----------------
__global__ __launch_bounds__(256) void ln_final_k(
    const float* __restrict__ X1,   // [4096,1024] pre-LN attn output
    const float* __restrict__ X2,   // [4096,1024] W2@ff + b2 (no residual yet)
    float* __restrict__ O)          // [b,1024,256]
{
    int row = blockIdx.x, t = threadIdx.x;
    int b = row >> 8, qq = row & 255;
    __shared__ float r1[256], r2[256];
    const float* x1 = X1 + (long long)row * 1024;
    const float* x2 = X2 + (long long)row * 1024;

    float v1[4], s = 0.f, ss = 0.f;
#pragma unroll
    for (int u = 0; u < 4; ++u) {
        v1[u] = x1[t + u * 256];
        s += v1[u]; ss += v1[u] * v1[u];
    }
    r1[t] = s; r2[t] = ss;
    __syncthreads();
    for (int off = 128; off > 0; off >>= 1) {
        if (t < off) { r1[t] += r1[t + off]; r2[t] += r2[t + off]; }
        __syncthreads();
    }
    float mean = r1[0] * (1.f / 1024.f);
    float var  = r2[0] * (1.f / 1024.f) - mean * mean;
    float rstd = rsqrtf(var + 1e-5f);
    __syncthreads();

    float y[4]; s = 0.f; ss = 0.f;
#pragma unroll
    for (int u = 0; u < 4; ++u) {
        y[u] = x2[t + u * 256] + (v1[u] - mean) * rstd;
        s += y[u]; ss += y[u] * y[u];
    }
    r1[t] = s; r2[t] = ss;
    __syncthreads();
    for (int off = 128; off > 0; off >>= 1) {
        if (t < off) { r1[t] += r1[t + off]; r2[t] += r2[t + off]; }
        __syncthreads();
    }
    float mean2 = r1[0] * (1.f / 1024.f);
    float var2  = r2[0] * (1.f / 1024.f) - mean2 * mean2;
    float rstd2 = rsqrtf(var2 + 1e-5f);

    float* ob = O + (long long)b * 1024 * 256 + qq;
#pragma unroll
    for (int u = 0; u < 4; ++u)
        ob[(long long)(t + u * 256) * 256] = (y[u] - mean2) * rstd2;
}

extern "C" void kernel_launch(void* const* d_in, const int* in_sizes, int n_in,
                              void* d_out, int out_size, void* d_ws, size_t ws_size,
                              hipStream_t stream) {
    const float* z1ss    = (const float*)d_in[0];   // [16,1024,256]
    const float* uss     = (const float*)d_in[1];   // [16,3072,512]
    const float* mems    = (const float*)d_in[2];   // [16,1024,256]
    const float* pos_emb = (const float*)d_in[3];   // [1024,512]
    const float* Wqkv    = (const float*)d_in[4];   // [3072,1024]
    const float* Wr      = (const float*)d_in[5];   // [1024,1024]
    const float* Wo      = (const float*)d_in[6];   // [1024,1024]
    const float* bo      = (const float*)d_in[7];   // [1024]
    const float* rwb     = (const float*)d_in[8];   // [16,64]
    const float* rrb     = (const float*)d_in[9];   // [16,64]
    const float* W1      = (const float*)d_in[10];  // [4096,1024]
    const float* b1      = (const float*)d_in[11];  // [4096]
    const float* W2      = (const float*)d_in[12];  // [1024,4096]
    const float* b2      = (const float*)d_in[13];  // [1024]

    char* base = (char*)d_ws;
    // Workspace map (bytes). Total 121,634,816. Aliases:
    //   x2  @ catT  (catT dead after producer GEMMs)
    //   ff  @ kT+vB (dead after attention)
    // kT tile-edge OOB reads (<=2KB) land in vB; vB's (<=16B) land in rhkT: safe.
    bf16*  catT  = (bf16*) (base + 0);               // [16,512,1024]  16.8MB
    float* x2    = (float*)(base + 0);               // [4096,1024]    16.8MB
    bf16*  posT  = (bf16*) (base + 16777216);        // [512,1024]      1MB
    bf16*  WqkvB = (bf16*) (base + 17825792);        // [3072,1024]
    bf16*  WrB   = (bf16*) (base + 24117248);        // [1024,1024]
    bf16*  WoB   = (bf16*) (base + 26214400);        // [1024,1024]
    bf16*  W1B   = (bf16*) (base + 28311552);        // [4096,1024]
    bf16*  W2B   = (bf16*) (base + 36700160);        // [1024,4096]
    bf16*  qTB   = (bf16*) (base + 45088768);        // [16,256,1024]  8.4MB
    bf16*  kTB   = (bf16*) (base + 53477376);        // [16,512,1024]  16.8MB
    bf16*  vBB   = (bf16*) (base + 70254592);        // [16,1024,512]  16.8MB
    bf16*  ff_b  = (bf16*) (base + 53477376);        // [4096,4096] overlays kT+vB
    bf16*  rhkTB = (bf16*) (base + 87031808);        // [512,1024]      1MB
    bf16*  avTB  = (bf16*) (base + 88080384);        // [4096,1024]    8.4MB
    float* x1    = (float*)(base + 96468992);        // [4096,1024]    16.8MB
    bf16*  hB    = (bf16*) (base + 113246208);       // [4096,1024]    8.4MB

    // ---- weight casts ----
    cast_bf16_k<<<(3072 * 1024 / 4 + 255) / 256, 256, 0, stream>>>(Wqkv, WqkvB, 3072 * 1024 / 4);
    cast_bf16_k<<<(1024 * 1024 / 4 + 255) / 256, 256, 0, stream>>>(Wr, WrB, 1024 * 1024 / 4);
    cast_bf16_k<<<(1024 * 1024 / 4 + 255) / 256, 256, 0, stream>>>(Wo, WoB, 1024 * 1024 / 4);
    cast_bf16_k<<<(4096 * 1024 / 4 + 255) / 256, 256, 0, stream>>>(W1, W1B, 4096 * 1024 / 4);
    cast_bf16_k<<<(4096 * 1024 / 4 + 255) / 256, 256, 0, stream>>>(W2, W2B, 4096 * 1024 / 4);

    // ---- transposed bf16 activations: catT rows 0..255 = memsT, 256..511 = z1ssT ----
    transpose_cast_k<<<dim3(256 / 32, 1024 / 32, BSZ), 256, 0, stream>>>(
        mems, 1024LL * 256, 256, catT, 512LL * 1024, 1024);
    transpose_cast_k<<<dim3(256 / 32, 1024 / 32, BSZ), 256, 0, stream>>>(
        z1ss, 1024LL * 256, 256, catT + 256 * 1024, 512LL * 1024, 1024);
    transpose_cast_k<<<dim3(512 / 32, 1024 / 32, 1), 256, 0, stream>>>(
        pos_emb, 0, 512, posT, 0, 1024);

    // ---- qT[b,i,dg] = z1ssT @ Wqkv[0:1024]^T + uss[dg, 256+i] ----
    gemm_bf16<<<dim3(8, 2, BSZ), 256, 0, stream>>>(
        catT + 256 * 1024, 512LL * 1024, WqkvB, 0,
        256, 1024, 1024,
        nullptr, uss, 3072LL * 512, 512, 256, 3, 0,
        nullptr, 0, qTB, 256LL * 1024);

    // ---- kT[b,j,dg] = catT @ Wqkv[1024:2048]^T + uss[1024+dg, j] ----
    gemm_bf16<<<dim3(8, 4, BSZ), 256, 0, stream>>>(
        catT, 512LL * 1024, WqkvB + 1024 * 1024, 0,
        512, 1024, 1024,
        nullptr, uss + 1024 * 512, 3072LL * 512, 512, 0, 3, 0,
        nullptr, 0, kTB, 512LL * 1024);

    // ---- vB[b,dg,j] = Wqkv[2048:3072] @ catT^T + uss[2048+dg, j] ----
    gemm_bf16<<<dim3(4, 8, BSZ), 256, 0, stream>>>(
        WqkvB + 2048 * 1024, 0, catT, 512LL * 1024,
        1024, 512, 1024,
        nullptr, uss + 2048 * 512, 3072LL * 512, 512, 0, 1, 0,
        nullptr, 0, vBB, 1024LL * 512);

    // ---- rhkT[jj,dg] = posT @ Wr^T ----
    gemm_bf16<<<dim3(8, 4, 1), 256, 0, stream>>>(
        posT, 0, WrB, 0,
        512, 1024, 1024,
        nullptr, nullptr, 0, 0, 0, 0, 0,
        nullptr, 0, rhkTB, 0);

    // ---- MFMA banded attention -> avT bf16 [bq, nd] ----
    attn_mfma_k<<<dim3(4, NHEAD, BSZ), 256, 0, stream>>>(
        qTB, kTB, vBB, rhkTB, rwb, rrb, avTB);

    // ---- x1[bq,1024] = avT @ Wo^T + bo + z1ss^T ----
    gemm_bf16<<<dim3(8, 32, 1), 256, 0, stream>>>(
        avTB, 0, WoB, 0,
        4096, 1024, 1024,
        bo, z1ss, 0, 0, 0, 2, 0,
        x1, 0, nullptr, 0);

    // ---- h = LN(x1) -> bf16 ----
    ln_bf16_k<<<4096, 256, 0, stream>>>(x1, hB);

    // ---- ff = relu(h @ W1^T + b1) -> bf16 ----
    gemm_bf16<<<dim3(32, 32, 1), 256, 0, stream>>>(
        hB, 0, W1B, 0,
        4096, 4096, 1024,
        b1, nullptr, 0, 0, 0, 0, 1,
        nullptr, 0, ff_b, 0);

    // ---- x2 = ff @ W2^T + b2 (residual h added in final kernel) ----
    gemm_bf16<<<dim3(8, 32, 1), 256, 0, stream>>>(
        ff_b, 0, W2B, 0,
        4096, 1024, 4096,
        b2, nullptr, 0, 0, 0, 0, 0,
        x2, 0, nullptr, 0);

    // ---- out = LN(x2 + LN(x1)) transposed to [b,d,q] ----
    ln_final_k<<<4096, 256, 0, stream>>>(x1, x2, (float*)d_out);
}

// Round 4
// 721.821 us; speedup vs baseline: 3.5298x; 1.0659x over previous
//
#include <hip/hip_runtime.h>
#include <hip/hip_bf16.h>
#include <math.h>

// Problem dims (fixed by setup_inputs)
#define BSZ    16
#define DMODEL 1024
#define QLEN   256
#define MLEN   256
#define KLEN   512
#define NHEAD  16
#define DHEAD  64
#define DINNER 4096

typedef __bf16 bf16;
typedef bf16 bf16x8 __attribute__((ext_vector_type(8)));
typedef float f32x4 __attribute__((ext_vector_type(4)));

#define GLOBAL_AS __attribute__((address_space(1)))
#define LDS_AS    __attribute__((address_space(3)))

// ---------------- fused fp32->bf16 cast of all 5 weight matrices ----------------
// float4 ranges: Wqkv 786432 | Wr 262144 | Wo 262144 | W1 1048576 | W2 1048576
__global__ __launch_bounds__(256) void cast_all_k(
    const float* __restrict__ w0, const float* __restrict__ w1,
    const float* __restrict__ w2, const float* __restrict__ w3,
    const float* __restrict__ w4,
    bf16* __restrict__ o0, bf16* __restrict__ o1, bf16* __restrict__ o2,
    bf16* __restrict__ o3, bf16* __restrict__ o4)
{
    long long i = (long long)blockIdx.x * 256 + threadIdx.x;
    const float* src; bf16* dst; long long off;
    if      (i <  786432) { src = w0; dst = o0; off = i; }
    else if (i < 1048576) { src = w1; dst = o1; off = i -  786432; }
    else if (i < 1310720) { src = w2; dst = o2; off = i - 1048576; }
    else if (i < 2359296) { src = w3; dst = o3; off = i - 1310720; }
    else                  { src = w4; dst = o4; off = i - 2359296; }
    float4 v = ((const float4*)src)[off];
    bf16 b0 = (bf16)v.x, b1 = (bf16)v.y, b2 = (bf16)v.z, b3 = (bf16)v.w;
    union { ushort u[4]; uint2 d; } p;
    p.u[0] = *(ushort*)&b0; p.u[1] = *(ushort*)&b1;
    p.u[2] = *(ushort*)&b2; p.u[3] = *(ushort*)&b3;
    ((uint2*)dst)[off] = p.d;
}

// ---------------- mems+z1ss -> catT transpose-cast (merged, z=32) ----------------
__global__ __launch_bounds__(256) void transpose_cat_k(
    const float* __restrict__ mems, const float* __restrict__ z1ss,
    bf16* __restrict__ catT)
{
    __shared__ float tile[32][33];
    int zz = blockIdx.z, b = zz >> 1, half = zz & 1;
    const float* ip = (half ? z1ss : mems) + (long long)b * 1024 * 256;
    bf16* op = catT + (long long)b * 512 * 1024 + (long long)half * 256 * 1024;
    int tx = threadIdx.x & 31, ty = threadIdx.x >> 5;
    int r0 = blockIdx.y * 32, c0 = blockIdx.x * 32;   // r over d(1024), c over i(256)
#pragma unroll
    for (int yy = ty; yy < 32; yy += 8)
        tile[yy][tx] = ip[(long long)(r0 + yy) * 256 + c0 + tx];
    __syncthreads();
#pragma unroll
    for (int yy = ty; yy < 32; yy += 8)
        op[(long long)(c0 + yy) * 1024 + r0 + tx] = (bf16)tile[tx][yy];
}

// ---------------- generic fp32 [R,C] -> bf16 [C,R] transpose-cast ----------------
__global__ __launch_bounds__(256) void transpose_cast_k(
    const float* __restrict__ in, int ldi,
    bf16* __restrict__ out, int ldo)
{
    __shared__ float tile[32][33];
    int tx = threadIdx.x & 31, ty = threadIdx.x >> 5;
    int r0 = blockIdx.y * 32, c0 = blockIdx.x * 32;
#pragma unroll
    for (int yy = ty; yy < 32; yy += 8)
        tile[yy][tx] = in[(long long)(r0 + yy) * ldi + c0 + tx];
    __syncthreads();
#pragma unroll
    for (int yy = ty; yy < 32; yy += 8)
        out[(long long)(c0 + yy) * ldo + r0 + tx] = (bf16)tile[tx][yy];
}

// ---------------- bf16 MFMA GEMM: C[M,N] = A[M,K] * B[N,K]^T ----------------
// 128x128 tile, BK=32, 4 waves (2x2), 16x16x32 MFMA, global_load_lds staging.
// kChunk>0: blockIdx.z = K-chunk (split-K; A/B lead dim stays K; outF gets
//           per-chunk partial at +bz*ofBatch). kChunk==0: blockIdx.z = batch.
// emode 1: +E[m*ldE+n] (per-batch fp32); emode 3: +E[n*ldE+m+eOff] (uss^T).
// omode 1: merged qk output split -> outB=qT (n<1024, m>=256), outB2=kT (n>=1024);
//          dead blocks (m0<256 && n0<1024) early-exit.
__global__ __launch_bounds__(256) void gemm_bf16(
    const bf16* __restrict__ A, long long aBatch,
    const bf16* __restrict__ B, long long bBatch,
    int M, int N, int K, int kChunk,
    const float* __restrict__ bias,
    const float* __restrict__ E, long long eBatch, int ldE, int eOff, int emode,
    int relu,
    float* __restrict__ outF, long long ofBatch,
    bf16* __restrict__ outB, long long obBatch,
    int omode, bf16* __restrict__ outB2)
{
    int t = threadIdx.x;
    int w = t >> 6, lane = t & 63;
    int m0 = blockIdx.y * 128, n0 = blockIdx.x * 128;
    int bz = blockIdx.z;

    if (omode == 1 && m0 < 256 && n0 < 1024) return;  // dead q-region blocks

    __shared__ bf16 lA[128 * 32];
    __shared__ bf16 lB[128 * 32];

    const bf16* Ap; const bf16* Bp;
    float* oF = outF;
    bf16*  oB = outB;
    const float* Ep = E;
    int Keff = K;
    if (kChunk > 0) {
        Ap = A + (long long)bz * kChunk;
        Bp = B + (long long)bz * kChunk;
        if (outF) oF = outF + (long long)bz * ofBatch;
        Keff = kChunk;
    } else {
        Ap = A + (long long)bz * aBatch;
        Bp = B + (long long)bz * bBatch;
        if (E)    Ep = E + (long long)bz * eBatch;
        if (outF) oF = outF + (long long)bz * ofBatch;
        if (outB && omode == 0) oB = outB + (long long)bz * obBatch;
    }

    int q = lane >> 4, r16 = lane & 15;
    int wm = w >> 1, wn = w & 1;

    f32x4 acc[4][4];
#pragma unroll
    for (int i = 0; i < 4; ++i)
#pragma unroll
        for (int j = 0; j < 4; ++j)
            acc[i][j] = (f32x4){0.f, 0.f, 0.f, 0.f};

    int srow = (lane >> 2);        // row within 16-row chunk
    int scol = (lane & 3) * 8;     // element col within 32

    for (int k0 = 0; k0 < Keff; k0 += 32) {
        __syncthreads();
#pragma unroll
        for (int issue = 0; issue < 2; ++issue) {
            int c = issue * 4 + w;           // chunk 0..7 (16 rows each)
            int row = c * 16 + srow;
            __builtin_amdgcn_global_load_lds(
                (const GLOBAL_AS void*)(Ap + (long long)(m0 + row) * K + k0 + scol),
                (LDS_AS void*)(lA + c * 512 + lane * 8), 16, 0, 0);
            __builtin_amdgcn_global_load_lds(
                (const GLOBAL_AS void*)(Bp + (long long)(n0 + row) * K + k0 + scol),
                (LDS_AS void*)(lB + c * 512 + lane * 8), 16, 0, 0);
        }
        __syncthreads();

        bf16x8 af[4], bfr[4];
#pragma unroll
        for (int i = 0; i < 4; ++i)
            af[i] = *(const bf16x8*)&lA[(wm * 64 + i * 16 + r16) * 32 + q * 8];
#pragma unroll
        for (int j = 0; j < 4; ++j)
            bfr[j] = *(const bf16x8*)&lB[(wn * 64 + j * 16 + r16) * 32 + q * 8];
#pragma unroll
        for (int i = 0; i < 4; ++i)
#pragma unroll
            for (int j = 0; j < 4; ++j)
                acc[i][j] = __builtin_amdgcn_mfma_f32_16x16x32_bf16(
                    af[i], bfr[j], acc[i][j], 0, 0, 0);
    }

#pragma unroll
    for (int i = 0; i < 4; ++i) {
#pragma unroll
        for (int r = 0; r < 4; ++r) {
            int m = m0 + wm * 64 + i * 16 + q * 4 + r;
#pragma unroll
            for (int j = 0; j < 4; ++j) {
                int n = n0 + wn * 64 + j * 16 + r16;
                float v = acc[i][j][r];
                if (bias) v += bias[n];
                if (emode == 1)      v += Ep[(long long)m * ldE + n];
                else if (emode == 3) v += Ep[(long long)n * ldE + m + eOff];
                if (relu) v = fmaxf(v, 0.f);
                if (omode == 1) {
                    if (n < 1024) {
                        if (m >= 256)
                            outB[((long long)bz * 256 + (m - 256)) * 1024 + n] = (bf16)v;
                    } else {
                        outB2[((long long)bz * 512 + m) * 1024 + (n - 1024)] = (bf16)v;
                    }
                } else {
                    if (oF) oF[(long long)m * N + n] = v;
                    if (oB) oB[(long long)m * N + n] = (bf16)v;
                }
            }
        }
    }
}

// ---------------- MFMA banded-window rel-pos attention ----------------
__global__ __launch_bounds__(256) void attn_mfma_k(
    const bf16* __restrict__ qT,    // [b,256,1024]
    const bf16* __restrict__ kT,    // [b,512,1024]
    const bf16* __restrict__ vB,    // [b,1024,512]
    const bf16* __restrict__ rhkT,  // [512,1024]
    const float* __restrict__ rwb,  // [16,64]
    const float* __restrict__ rrb,  // [16,64]
    bf16* __restrict__ avT)         // [(b*256+i)*1024 + n*64+d]
{
    __shared__ float sBD[64][132];

    int t = threadIdx.x;
    int w = t >> 6, lane = t & 63;
    int lo = lane & 15, hi = lane >> 4;
    int i0 = blockIdx.x * 64;
    int n  = blockIdx.y;
    int b  = blockIdx.z;

    const bf16* qp = qT + ((long long)(b * 256 + i0 + 16 * w + lo)) * 1024 + n * 64;
    bf16x8 qw[2], qr[2];
#pragma unroll
    for (int ks = 0; ks < 2; ++ks) {
        bf16x8 qv = *(const bf16x8*)(qp + ks * 32 + hi * 8);
        const float* wb = rwb + n * 64 + ks * 32 + hi * 8;
        const float* rb = rrb + n * 64 + ks * 32 + hi * 8;
#pragma unroll
        for (int e = 0; e < 8; ++e) {
            float qf = (float)qv[e];
            qw[ks][e] = (bf16)(qf + wb[e]);
            qr[ks][e] = (bf16)(qf + rb[e]);
        }
    }

    const bf16* rp = rhkT + (long long)384 * 1024 + n * 64;
#pragma unroll
    for (int tj = 0; tj < 8; ++tj) {
        const bf16* bp = rp + (long long)(16 * tj + lo) * 1024;
        f32x4 a = (f32x4){0.f, 0.f, 0.f, 0.f};
        a = __builtin_amdgcn_mfma_f32_16x16x32_bf16(qr[0], *(const bf16x8*)(bp + hi * 8), a, 0, 0, 0);
        a = __builtin_amdgcn_mfma_f32_16x16x32_bf16(qr[1], *(const bf16x8*)(bp + 32 + hi * 8), a, 0, 0, 0);
#pragma unroll
        for (int r = 0; r < 4; ++r)
            sBD[16 * w + hi * 4 + r][16 * tj + lo] = a[r];
    }
    __syncthreads();

    f32x4 ac[12];
    const bf16* kp = kT + ((long long)b * 512 + i0 + 129) * 1024 + n * 64;
#pragma unroll
    for (int tj = 0; tj < 12; ++tj) {
        const bf16* bp = kp + (long long)(16 * tj + lo) * 1024;
        f32x4 a = (f32x4){0.f, 0.f, 0.f, 0.f};
        a = __builtin_amdgcn_mfma_f32_16x16x32_bf16(qw[0], *(const bf16x8*)(bp + hi * 8), a, 0, 0, 0);
        a = __builtin_amdgcn_mfma_f32_16x16x32_bf16(qw[1], *(const bf16x8*)(bp + 32 + hi * 8), a, 0, 0, 0);
        ac[tj] = a;
    }

    float p[12][4], rowmax[4], rowsum[4];
#pragma unroll
    for (int r = 0; r < 4; ++r) rowmax[r] = -1e30f;
#pragma unroll
    for (int tj = 0; tj < 12; ++tj) {
#pragma unroll
        for (int r = 0; r < 4; ++r) {
            int m = 16 * w + hi * 4 + r;
            int jj = 16 * tj + lo;
            int tt = jj - m;
            float v = (tt >= 0 && tt < 128) ? (ac[tj][r] + sBD[m][tt]) * 0.125f
                                            : -1e30f;
            p[tj][r] = v;
            rowmax[r] = fmaxf(rowmax[r], v);
        }
    }
#pragma unroll
    for (int r = 0; r < 4; ++r) {
        float mx = rowmax[r];
#pragma unroll
        for (int msk = 1; msk < 16; msk <<= 1)
            mx = fmaxf(mx, __shfl_xor(mx, msk, 64));
        rowmax[r] = mx;
        rowsum[r] = 0.f;
    }
#pragma unroll
    for (int tj = 0; tj < 12; ++tj) {
#pragma unroll
        for (int r = 0; r < 4; ++r) {
            float e = exp2f((p[tj][r] - rowmax[r]) * 1.44269504f);
            p[tj][r] = e;
            rowsum[r] += e;
        }
    }
#pragma unroll
    for (int r = 0; r < 4; ++r) {
        float s = rowsum[r];
#pragma unroll
        for (int msk = 1; msk < 16; msk <<= 1)
            s += __shfl_xor(s, msk, 64);
        rowsum[r] = 1.f / s;
    }

    bf16* P = (bf16*)&sBD[0][0];
#pragma unroll
    for (int tj = 0; tj < 12; ++tj) {
#pragma unroll
        for (int r = 0; r < 4; ++r) {
            int m = 16 * w + hi * 4 + r;
            P[m * 264 + 16 * tj + lo] = (bf16)(p[tj][r] * rowsum[r]);
        }
    }
    __syncthreads();

    f32x4 oacc[4];
#pragma unroll
    for (int td = 0; td < 4; ++td) oacc[td] = (f32x4){0.f, 0.f, 0.f, 0.f};
    const bf16* vp = vB + ((long long)b * 1024 + n * 64) * 512 + i0 + 129;
#pragma unroll
    for (int ks = 0; ks < 6; ++ks) {
        bf16x8 af = *(const bf16x8*)(P + (16 * w + lo) * 264 + ks * 32 + hi * 8);
#pragma unroll
        for (int td = 0; td < 4; ++td) {
            bf16x8 bv = *(const bf16x8*)(vp + (long long)(16 * td + lo) * 512 + ks * 32 + hi * 8);
            oacc[td] = __builtin_amdgcn_mfma_f32_16x16x32_bf16(af, bv, oacc[td], 0, 0, 0);
        }
    }
    bf16* op = avT + ((long long)(b * 256 + i0 + 16 * w)) * 1024 + n * 64;
#pragma unroll
    for (int td = 0; td < 4; ++td)
#pragma unroll
        for (int r = 0; r < 4; ++r)
            op[(long long)(hi * 4 + r) * 1024 + 16 * td + lo] = (bf16)oacc[td][r];
}

// ------- h = LN(x1a+x1b+bo+z1ssT) -> bf16;  rows of [4096,1024] -------
__global__ __launch_bounds__(256) void ln_bf16_k(
    const float* __restrict__ X1a, const float* __restrict__ X1b,
    const float* __restrict__ bo,  const bf16* __restrict__ catT,
    bf16* __restrict__ H)
{
    int row = blockIdx.x, t = threadIdx.x;
    __shared__ float r1[256], r2[256];
    const float* xa = X1a + (long long)row * 1024;
    const float* xb = X1b + (long long)row * 1024;
    const bf16*  zr = catT + ((long long)(row >> 8) * 512 + 256 + (row & 255)) * 1024;
    float v[4], s = 0.f, ss = 0.f;
#pragma unroll
    for (int u = 0; u < 4; ++u) {
        int c = t + u * 256;
        v[u] = xa[c] + xb[c] + bo[c] + (float)zr[c];
        s += v[u]; ss += v[u] * v[u];
    }
    r1[t] = s; r2[t] = ss;
    __syncthreads();
    for (int off = 128; off > 0; off >>= 1) {
        if (t < off) { r1[t] += r1[t + off]; r2[t] += r2[t + off]; }
        __syncthreads();
    }
    float mean = r1[0] * (1.f / 1024.f);
    float var  = r2[0] * (1.f / 1024.f) - mean * mean;
    float rstd = rsqrtf(var + 1e-5f);
    bf16* hr = H + (long long)row * 1024;
#pragma unroll
    for (int u = 0; u < 4; ++u)
        hr[t + u * 256] = (bf16)((v[u] - mean) * rstd);
}

// ------- out = LN(x2a+x2b+b2+h) transposed to [b,d,q] -------
__global__ __launch_bounds__(256) void ln_final_k(
    const bf16* __restrict__ Hb,
    const float* __restrict__ X2a, const float* __restrict__ X2b,
    const float* __restrict__ b2,
    float* __restrict__ O)
{
    int row = blockIdx.x, t = threadIdx.x;
    int b = row >> 8, qq = row & 255;
    __shared__ float r1[256], r2[256];
    const float* xa = X2a + (long long)row * 1024;
    const float* xb = X2b + (long long)row * 1024;
    const bf16*  hr = Hb  + (long long)row * 1024;

    float y[4], s = 0.f, ss = 0.f;
#pragma unroll
    for (int u = 0; u < 4; ++u) {
        int c = t + u * 256;
        y[u] = xa[c] + xb[c] + b2[c] + (float)hr[c];
        s += y[u]; ss += y[u] * y[u];
    }
    r1[t] = s; r2[t] = ss;
    __syncthreads();
    for (int off = 128; off > 0; off >>= 1) {
        if (t < off) { r1[t] += r1[t + off]; r2[t] += r2[t + off]; }
        __syncthreads();
    }
    float mean = r1[0] * (1.f / 1024.f);
    float var  = r2[0] * (1.f / 1024.f) - mean * mean;
    float rstd = rsqrtf(var + 1e-5f);

    float* ob = O + (long long)b * 1024 * 256 + qq;
#pragma unroll
    for (int u = 0; u < 4; ++u)
        ob[(long long)(t + u * 256) * 256] = (y[u] - mean) * rstd;
}

extern "C" void kernel_launch(void* const* d_in, const int* in_sizes, int n_in,
                              void* d_out, int out_size, void* d_ws, size_t ws_size,
                              hipStream_t stream) {
    const float* z1ss    = (const float*)d_in[0];   // [16,1024,256]
    const float* uss     = (const float*)d_in[1];   // [16,3072,512]
    const float* mems    = (const float*)d_in[2];   // [16,1024,256]
    const float* pos_emb = (const float*)d_in[3];   // [1024,512]
    const float* Wqkv    = (const float*)d_in[4];   // [3072,1024]
    const float* Wr      = (const float*)d_in[5];   // [1024,1024]
    const float* Wo      = (const float*)d_in[6];   // [1024,1024]
    const float* bo      = (const float*)d_in[7];   // [1024]
    const float* rwb     = (const float*)d_in[8];   // [16,64]
    const float* rrb     = (const float*)d_in[9];   // [16,64]
    const float* W1      = (const float*)d_in[10];  // [4096,1024]
    const float* b1      = (const float*)d_in[11];  // [4096]
    const float* W2      = (const float*)d_in[12];  // [1024,4096]
    const float* b2      = (const float*)d_in[13];  // [1024]

    char* base = (char*)d_ws;
    // Workspace map (bytes), total 138,412,032 (132 MB). Timeline aliases:
    //   x1a/x1b overlay kTB/vBB   (written by Wo after attention reads k/v)
    //   ff_b    overlays kTB+vBB  (written by FF1 after ln_bf16 consumed x1a/b)
    bf16*  catT  = (bf16*) (base + 0);               // [16,512,1024]  alive thru ln_bf16
    bf16*  posT  = (bf16*) (base + 16777216);        // [512,1024]
    bf16*  WqkvB = (bf16*) (base + 17825792);        // [3072,1024]
    bf16*  WrB   = (bf16*) (base + 24117248);        // [1024,1024]
    bf16*  WoB   = (bf16*) (base + 26214400);        // [1024,1024]
    bf16*  W1B   = (bf16*) (base + 28311552);        // [4096,1024]
    bf16*  W2B   = (bf16*) (base + 36700160);        // [1024,4096]
    bf16*  qTB   = (bf16*) (base + 45088768);        // [16,256,1024]
    bf16*  kTB   = (bf16*) (base + 53477376);        // [16,512,1024]
    bf16*  vBB   = (bf16*) (base + 70254592);        // [16,1024,512]
    float* x1a   = (float*)(base + 53477376);        // [4096,1024] overlays kTB
    float* x1b   = (float*)(base + 70254592);        // [4096,1024] overlays vBB
    bf16*  ff_b  = (bf16*) (base + 53477376);        // [4096,4096] overlays kTB+vBB
    bf16*  rhkTB = (bf16*) (base + 87031808);        // [512,1024]
    bf16*  avTB  = (bf16*) (base + 88080384);        // [4096,1024]
    float* x2a   = (float*)(base + 96468992);        // [4096,1024]
    float* x2b   = (float*)(base + 113246208);       // [4096,1024]
    bf16*  hB    = (bf16*) (base + 130023424);       // [4096,1024]

    // ---- all weight casts in one launch ----
    cast_all_k<<<3407872 / 256, 256, 0, stream>>>(
        Wqkv, Wr, Wo, W1, W2, WqkvB, WrB, WoB, W1B, W2B);

    // ---- transposed bf16 activations ----
    transpose_cat_k<<<dim3(8, 32, 32), 256, 0, stream>>>(mems, z1ss, catT);
    transpose_cast_k<<<dim3(16, 32, 1), 256, 0, stream>>>(pos_emb, 512, posT, 1024);

    // ---- merged qk GEMM: C[m,n] = catT[m,:]·Wqkv[n,:] + uss[b,n,m] ----
    // n<1024 & m>=256 -> qT[b, m-256, n];  n>=1024 -> kT[b, m, n-1024]
    gemm_bf16<<<dim3(16, 4, BSZ), 256, 0, stream>>>(
        catT, 512LL * 1024, WqkvB, 0,
        512, 2048, 1024, 0,
        nullptr, uss, 3072LL * 512, 512, 0, 3, 0,
        nullptr, 0, qTB, 0, 1, kTB);

    // ---- vB[b,dg,j] = Wqkv[2048:3072] @ catT^T + uss[2048+dg, j] ----
    gemm_bf16<<<dim3(4, 8, BSZ), 256, 0, stream>>>(
        WqkvB + 2048 * 1024, 0, catT, 512LL * 1024,
        1024, 512, 1024, 0,
        nullptr, uss + 2048 * 512, 3072LL * 512, 512, 0, 1, 0,
        nullptr, 0, vBB, 1024LL * 512, 0, nullptr);

    // ---- rhkT[jj,dg] = posT @ Wr^T ----
    gemm_bf16<<<dim3(8, 4, 1), 256, 0, stream>>>(
        posT, 0, WrB, 0,
        512, 1024, 1024, 0,
        nullptr, nullptr, 0, 0, 0, 0, 0,
        nullptr, 0, rhkTB, 0, 0, nullptr);

    // ---- MFMA banded attention -> avT bf16 [bq, nd] ----
    attn_mfma_k<<<dim3(4, NHEAD, BSZ), 256, 0, stream>>>(
        qTB, kTB, vBB, rhkTB, rwb, rrb, avTB);

    // ---- x1 partials = avT @ Wo^T  (split-K=2; bias+residual in ln_bf16) ----
    gemm_bf16<<<dim3(8, 32, 2), 256, 0, stream>>>(
        avTB, 0, WoB, 0,
        4096, 1024, 1024, 512,
        nullptr, nullptr, 0, 0, 0, 0, 0,
        x1a, (long long)(x1b - x1a), nullptr, 0, 0, nullptr);

    // ---- h = LN(x1a+x1b+bo+z1ssT) -> bf16 ----
    ln_bf16_k<<<4096, 256, 0, stream>>>(x1a, x1b, bo, catT, hB);

    // ---- ff = relu(h @ W1^T + b1) -> bf16 ----
    gemm_bf16<<<dim3(32, 32, 1), 256, 0, stream>>>(
        hB, 0, W1B, 0,
        4096, 4096, 1024, 0,
        b1, nullptr, 0, 0, 0, 0, 1,
        nullptr, 0, ff_b, 0, 0, nullptr);

    // ---- x2 partials = ff @ W2^T  (split-K=2; bias+residual in ln_final) ----
    gemm_bf16<<<dim3(8, 32, 2), 256, 0, stream>>>(
        ff_b, 0, W2B, 0,
        4096, 1024, 4096, 2048,
        nullptr, nullptr, 0, 0, 0, 0, 0,
        x2a, (long long)(x2b - x2a), nullptr, 0, 0, nullptr);

    // ---- out = LN(x2a+x2b+b2+h) transposed to [b,d,q] ----
    ln_final_k<<<4096, 256, 0, stream>>>(hB, x2a, x2b, b2, (float*)d_out);
}

// Round 5
// 682.698 us; speedup vs baseline: 3.7320x; 1.0573x over previous
//
#include <hip/hip_runtime.h>
#include <hip/hip_bf16.h>
#include <math.h>

// Problem dims (fixed by setup_inputs)
#define BSZ    16
#define DMODEL 1024
#define QLEN   256
#define MLEN   256
#define KLEN   512
#define NHEAD  16
#define DHEAD  64
#define DINNER 4096

typedef __bf16 bf16;
typedef bf16 bf16x8 __attribute__((ext_vector_type(8)));
typedef float f32x4 __attribute__((ext_vector_type(4)));

#define GLOBAL_AS __attribute__((address_space(1)))
#define LDS_AS    __attribute__((address_space(3)))

// -------- prep_flat: straight fp32->bf16 casts (5 weights + uss v-part) --------
// float4 units: Wqkv 786432 | Wr 262144 | Wo 262144 | W1 1048576 | W2 1048576
// | ussV 16*131072 (per-batch src offset b*393216 + 262144)
__global__ __launch_bounds__(256) void prep_flat_k(
    const float* __restrict__ w0, const float* __restrict__ w1,
    const float* __restrict__ w2, const float* __restrict__ w3,
    const float* __restrict__ w4, const float* __restrict__ uss,
    bf16* __restrict__ o0, bf16* __restrict__ o1, bf16* __restrict__ o2,
    bf16* __restrict__ o3, bf16* __restrict__ o4, bf16* __restrict__ oV)
{
    long long i = (long long)blockIdx.x * 256 + threadIdx.x;
    const float* src; bf16* dst; long long soff, doff;
    if      (i <  786432) { src = w0; dst = o0; soff = doff = i; }
    else if (i < 1048576) { src = w1; dst = o1; soff = doff = i -  786432; }
    else if (i < 1310720) { src = w2; dst = o2; soff = doff = i - 1048576; }
    else if (i < 2359296) { src = w3; dst = o3; soff = doff = i - 1310720; }
    else if (i < 3407872) { src = w4; dst = o4; soff = doff = i - 2359296; }
    else {
        long long u = i - 3407872, b = u >> 17, r = u & 131071;
        src = uss; dst = oV; soff = b * 393216 + 262144 + r; doff = u;
    }
    float4 v = ((const float4*)src)[soff];
    bf16 b0 = (bf16)v.x, b1 = (bf16)v.y, b2 = (bf16)v.z, b3 = (bf16)v.w;
    union { ushort u[4]; uint2 d; } p;
    p.u[0] = *(ushort*)&b0; p.u[1] = *(ushort*)&b1;
    p.u[2] = *(ushort*)&b2; p.u[3] = *(ushort*)&b3;
    ((uint2*)dst)[doff] = p.d;
}

// -------- prep_tr: all fp32->bf16 32x32 tile transposes --------
// regions: [0,8192) catT | [8192,8704) posT | [8704,12800) ussQ | [12800,20992) ussK
__global__ __launch_bounds__(256) void prep_tr_k(
    const float* __restrict__ mems, const float* __restrict__ z1ss,
    const float* __restrict__ pos_emb, const float* __restrict__ uss,
    bf16* __restrict__ catT, bf16* __restrict__ posT,
    bf16* __restrict__ ussQ, bf16* __restrict__ ussK)
{
    __shared__ float tile[32][33];
    int blk = blockIdx.x;
    const float* src; bf16* dst; long long soff, dof; int ld, ldo, tr, tc;
    if (blk < 8192) {            // catT: (b,half) src [1024,256] -> dst rows 256
        int bh = blk >> 8, t = blk & 255;
        int b = bh >> 1, half = bh & 1;
        tr = t >> 3; tc = t & 7;
        src = half ? z1ss : mems; soff = (long long)b * 1024 * 256; ld = 256;
        dst = catT; dof = ((long long)b * 512 + half * 256) * 1024; ldo = 1024;
    } else if (blk < 8704) {     // posT: [1024,512] -> [512,1024]
        int u = blk - 8192; tr = u >> 4; tc = u & 15;
        src = pos_emb; soff = 0; ld = 512;
        dst = posT; dof = 0; ldo = 1024;
    } else if (blk < 12800) {    // ussQ: uss[b, n<1024, 256+i] -> [b,i,n]
        int u = blk - 8704; int b = u >> 8, t = u & 255;
        tr = t >> 3; tc = t & 7;
        src = uss; soff = (long long)b * 3072 * 512 + 256; ld = 512;
        dst = ussQ; dof = (long long)b * 256 * 1024; ldo = 1024;
    } else {                     // ussK: uss[b, 1024+n, j] -> [b,j,n]
        int u = blk - 12800; int b = u >> 9, t = u & 511;
        tr = t >> 4; tc = t & 15;
        src = uss; soff = ((long long)b * 3072 + 1024) * 512; ld = 512;
        dst = ussK; dof = (long long)b * 512 * 1024; ldo = 1024;
    }
    int tx = threadIdx.x & 31, ty = threadIdx.x >> 5;
    const float* ip = src + soff;
#pragma unroll
    for (int yy = ty; yy < 32; yy += 8)
        tile[yy][tx] = ip[(long long)(tr * 32 + yy) * ld + tc * 32 + tx];
    __syncthreads();
#pragma unroll
    for (int yy = ty; yy < 32; yy += 8)
        dst[dof + (long long)(tc * 32 + yy) * ldo + tr * 32 + tx] = (bf16)tile[tx][yy];
}

// ---------------- bf16 MFMA GEMM: C[M,N] = A[M,K] * B[N,K]^T ----------------
// 128x128 tile, BK=32, 4 waves (2x2), 16x16x32 MFMA, global_load_lds staging.
// kChunk>0: blockIdx.z = K-chunk (split-K; partials to outF + bz*ofBatch).
// omode 0: batched; optional bf16 add Eb at the C store index.
// omode 1: merged qk; n<1024&m>=256 -> outB=qT (+EbQ), n>=1024 -> outB2=kT (+EbK);
//          dead blocks (m0<256&&n0<1024, bz<16) exit; bz==16 -> rhk mode:
//          A=A2 (posT), B=B2 (WrB), O2[m*1024+n], blocks with n0>=1024 exit.
__global__ __launch_bounds__(256) void gemm_bf16(
    const bf16* __restrict__ A, long long aBatch,
    const bf16* __restrict__ B, long long bBatch,
    int M, int N, int K, int kChunk,
    const float* __restrict__ bias,
    const bf16* __restrict__ Eb, long long ebBatch,
    int relu,
    float* __restrict__ outF, long long ofBatch,
    bf16* __restrict__ outB, long long obBatch,
    int omode, bf16* __restrict__ outB2,
    const bf16* __restrict__ EbQ, const bf16* __restrict__ EbK,
    const bf16* __restrict__ A2, const bf16* __restrict__ B2,
    bf16* __restrict__ O2)
{
    int t = threadIdx.x;
    int w = t >> 6, lane = t & 63;
    int m0 = blockIdx.y * 128, n0 = blockIdx.x * 128;
    int bz = blockIdx.z;
    bool rhk = (omode == 1) && (bz == 16);

    if (omode == 1 && !rhk && m0 < 256 && n0 < 1024) return;  // dead q-region
    if (rhk && n0 >= 1024) return;                            // rhk is N=1024

    __shared__ bf16 lA[128 * 32];
    __shared__ bf16 lB[128 * 32];

    const bf16* Ap; const bf16* Bp;
    float* oF = outF;
    bf16*  oB = outB;
    const bf16* Ebp = Eb;
    int Keff = K;
    if (rhk) {
        Ap = A2; Bp = B2;
    } else if (kChunk > 0) {
        Ap = A + (long long)bz * kChunk;
        Bp = B + (long long)bz * kChunk;
        if (outF) oF = outF + (long long)bz * ofBatch;
        Keff = kChunk;
    } else {
        Ap = A + (long long)bz * aBatch;
        Bp = B + (long long)bz * bBatch;
        if (Eb)   Ebp = Eb + (long long)bz * ebBatch;
        if (outF) oF = outF + (long long)bz * ofBatch;
        if (outB && omode == 0) oB = outB + (long long)bz * obBatch;
    }

    int q = lane >> 4, r16 = lane & 15;
    int wm = w >> 1, wn = w & 1;

    f32x4 acc[4][4];
#pragma unroll
    for (int i = 0; i < 4; ++i)
#pragma unroll
        for (int j = 0; j < 4; ++j)
            acc[i][j] = (f32x4){0.f, 0.f, 0.f, 0.f};

    int srow = (lane >> 2);
    int scol = (lane & 3) * 8;

    for (int k0 = 0; k0 < Keff; k0 += 32) {
        __syncthreads();
#pragma unroll
        for (int issue = 0; issue < 2; ++issue) {
            int c = issue * 4 + w;
            int row = c * 16 + srow;
            __builtin_amdgcn_global_load_lds(
                (const GLOBAL_AS void*)(Ap + (long long)(m0 + row) * K + k0 + scol),
                (LDS_AS void*)(lA + c * 512 + lane * 8), 16, 0, 0);
            __builtin_amdgcn_global_load_lds(
                (const GLOBAL_AS void*)(Bp + (long long)(n0 + row) * K + k0 + scol),
                (LDS_AS void*)(lB + c * 512 + lane * 8), 16, 0, 0);
        }
        __syncthreads();

        bf16x8 af[4], bfr[4];
#pragma unroll
        for (int i = 0; i < 4; ++i)
            af[i] = *(const bf16x8*)&lA[(wm * 64 + i * 16 + r16) * 32 + q * 8];
#pragma unroll
        for (int j = 0; j < 4; ++j)
            bfr[j] = *(const bf16x8*)&lB[(wn * 64 + j * 16 + r16) * 32 + q * 8];
#pragma unroll
        for (int i = 0; i < 4; ++i)
#pragma unroll
            for (int j = 0; j < 4; ++j)
                acc[i][j] = __builtin_amdgcn_mfma_f32_16x16x32_bf16(
                    af[i], bfr[j], acc[i][j], 0, 0, 0);
    }

#pragma unroll
    for (int i = 0; i < 4; ++i) {
#pragma unroll
        for (int r = 0; r < 4; ++r) {
            int m = m0 + wm * 64 + i * 16 + q * 4 + r;
#pragma unroll
            for (int j = 0; j < 4; ++j) {
                int n = n0 + wn * 64 + j * 16 + r16;
                float v = acc[i][j][r];
                if (bias) v += bias[n];
                if (relu) v = fmaxf(v, 0.f);
                if (rhk) {
                    O2[(long long)m * 1024 + n] = (bf16)v;
                } else if (omode == 1) {
                    if (n < 1024) {
                        if (m >= 256) {
                            long long idx = ((long long)(bz * 256 + m - 256) << 10) + n;
                            outB[idx] = (bf16)(v + (float)EbQ[idx]);
                        }
                    } else {
                        long long idx = ((long long)(bz * 512 + m) << 10) + (n - 1024);
                        outB2[idx] = (bf16)(v + (float)EbK[idx]);
                    }
                } else {
                    if (Eb) v += (float)Ebp[(long long)m * N + n];
                    if (oF) oF[(long long)m * N + n] = v;
                    if (oB) oB[(long long)m * N + n] = (bf16)v;
                }
            }
        }
    }
}

// ---------------- MFMA banded-window rel-pos attention ----------------
__global__ __launch_bounds__(256) void attn_mfma_k(
    const bf16* __restrict__ qT,    // [b,256,1024]
    const bf16* __restrict__ kT,    // [b,512,1024]
    const bf16* __restrict__ vB,    // [b,1024,512]
    const bf16* __restrict__ rhkT,  // [512,1024]
    const float* __restrict__ rwb,  // [16,64]
    const float* __restrict__ rrb,  // [16,64]
    bf16* __restrict__ avT)         // [(b*256+i)*1024 + n*64+d]
{
    __shared__ float sBD[64][132];

    int t = threadIdx.x;
    int w = t >> 6, lane = t & 63;
    int lo = lane & 15, hi = lane >> 4;
    int i0 = blockIdx.x * 64;
    int n  = blockIdx.y;
    int b  = blockIdx.z;

    const bf16* qp = qT + ((long long)(b * 256 + i0 + 16 * w + lo)) * 1024 + n * 64;
    bf16x8 qw[2], qr[2];
#pragma unroll
    for (int ks = 0; ks < 2; ++ks) {
        bf16x8 qv = *(const bf16x8*)(qp + ks * 32 + hi * 8);
        const float* wb = rwb + n * 64 + ks * 32 + hi * 8;
        const float* rb = rrb + n * 64 + ks * 32 + hi * 8;
#pragma unroll
        for (int e = 0; e < 8; ++e) {
            float qf = (float)qv[e];
            qw[ks][e] = (bf16)(qf + wb[e]);
            qr[ks][e] = (bf16)(qf + rb[e]);
        }
    }

    const bf16* rp = rhkT + (long long)384 * 1024 + n * 64;
#pragma unroll
    for (int tj = 0; tj < 8; ++tj) {
        const bf16* bp = rp + (long long)(16 * tj + lo) * 1024;
        f32x4 a = (f32x4){0.f, 0.f, 0.f, 0.f};
        a = __builtin_amdgcn_mfma_f32_16x16x32_bf16(qr[0], *(const bf16x8*)(bp + hi * 8), a, 0, 0, 0);
        a = __builtin_amdgcn_mfma_f32_16x16x32_bf16(qr[1], *(const bf16x8*)(bp + 32 + hi * 8), a, 0, 0, 0);
#pragma unroll
        for (int r = 0; r < 4; ++r)
            sBD[16 * w + hi * 4 + r][16 * tj + lo] = a[r];
    }
    __syncthreads();

    f32x4 ac[12];
    const bf16* kp = kT + ((long long)b * 512 + i0 + 129) * 1024 + n * 64;
#pragma unroll
    for (int tj = 0; tj < 12; ++tj) {
        const bf16* bp = kp + (long long)(16 * tj + lo) * 1024;
        f32x4 a = (f32x4){0.f, 0.f, 0.f, 0.f};
        a = __builtin_amdgcn_mfma_f32_16x16x32_bf16(qw[0], *(const bf16x8*)(bp + hi * 8), a, 0, 0, 0);
        a = __builtin_amdgcn_mfma_f32_16x16x32_bf16(qw[1], *(const bf16x8*)(bp + 32 + hi * 8), a, 0, 0, 0);
        ac[tj] = a;
    }

    float p[12][4], rowmax[4], rowsum[4];
#pragma unroll
    for (int r = 0; r < 4; ++r) rowmax[r] = -1e30f;
#pragma unroll
    for (int tj = 0; tj < 12; ++tj) {
#pragma unroll
        for (int r = 0; r < 4; ++r) {
            int m = 16 * w + hi * 4 + r;
            int jj = 16 * tj + lo;
            int tt = jj - m;
            float v = (tt >= 0 && tt < 128) ? (ac[tj][r] + sBD[m][tt]) * 0.125f
                                            : -1e30f;
            p[tj][r] = v;
            rowmax[r] = fmaxf(rowmax[r], v);
        }
    }
#pragma unroll
    for (int r = 0; r < 4; ++r) {
        float mx = rowmax[r];
#pragma unroll
        for (int msk = 1; msk < 16; msk <<= 1)
            mx = fmaxf(mx, __shfl_xor(mx, msk, 64));
        rowmax[r] = mx;
        rowsum[r] = 0.f;
    }
#pragma unroll
    for (int tj = 0; tj < 12; ++tj) {
#pragma unroll
        for (int r = 0; r < 4; ++r) {
            float e = exp2f((p[tj][r] - rowmax[r]) * 1.44269504f);
            p[tj][r] = e;
            rowsum[r] += e;
        }
    }
#pragma unroll
    for (int r = 0; r < 4; ++r) {
        float s = rowsum[r];
#pragma unroll
        for (int msk = 1; msk < 16; msk <<= 1)
            s += __shfl_xor(s, msk, 64);
        rowsum[r] = 1.f / s;
    }

    bf16* P = (bf16*)&sBD[0][0];
#pragma unroll
    for (int tj = 0; tj < 12; ++tj) {
#pragma unroll
        for (int r = 0; r < 4; ++r) {
            int m = 16 * w + hi * 4 + r;
            P[m * 264 + 16 * tj + lo] = (bf16)(p[tj][r] * rowsum[r]);
        }
    }
    __syncthreads();

    f32x4 oacc[4];
#pragma unroll
    for (int td = 0; td < 4; ++td) oacc[td] = (f32x4){0.f, 0.f, 0.f, 0.f};
    const bf16* vp = vB + ((long long)b * 1024 + n * 64) * 512 + i0 + 129;
#pragma unroll
    for (int ks = 0; ks < 6; ++ks) {
        bf16x8 af = *(const bf16x8*)(P + (16 * w + lo) * 264 + ks * 32 + hi * 8);
#pragma unroll
        for (int td = 0; td < 4; ++td) {
            bf16x8 bv = *(const bf16x8*)(vp + (long long)(16 * td + lo) * 512 + ks * 32 + hi * 8);
            oacc[td] = __builtin_amdgcn_mfma_f32_16x16x32_bf16(af, bv, oacc[td], 0, 0, 0);
        }
    }
    bf16* op = avT + ((long long)(b * 256 + i0 + 16 * w)) * 1024 + n * 64;
#pragma unroll
    for (int td = 0; td < 4; ++td)
#pragma unroll
        for (int r = 0; r < 4; ++r)
            op[(long long)(hi * 4 + r) * 1024 + 16 * td + lo] = (bf16)oacc[td][r];
}

// ------- h = LN(x1a+x1b+bo+z1ssT) -> bf16;  rows of [4096,1024] -------
__global__ __launch_bounds__(256) void ln_bf16_k(
    const float* __restrict__ X1a, const float* __restrict__ X1b,
    const float* __restrict__ bo,  const bf16* __restrict__ catT,
    bf16* __restrict__ H)
{
    int row = blockIdx.x, t = threadIdx.x;
    __shared__ float r1[256], r2[256];
    const float* xa = X1a + (long long)row * 1024;
    const float* xb = X1b + (long long)row * 1024;
    const bf16*  zr = catT + ((long long)(row >> 8) * 512 + 256 + (row & 255)) * 1024;
    float v[4], s = 0.f, ss = 0.f;
#pragma unroll
    for (int u = 0; u < 4; ++u) {
        int c = t + u * 256;
        v[u] = xa[c] + xb[c] + bo[c] + (float)zr[c];
        s += v[u]; ss += v[u] * v[u];
    }
    r1[t] = s; r2[t] = ss;
    __syncthreads();
    for (int off = 128; off > 0; off >>= 1) {
        if (t < off) { r1[t] += r1[t + off]; r2[t] += r2[t + off]; }
        __syncthreads();
    }
    float mean = r1[0] * (1.f / 1024.f);
    float var  = r2[0] * (1.f / 1024.f) - mean * mean;
    float rstd = rsqrtf(var + 1e-5f);
    bf16* hr = H + (long long)row * 1024;
#pragma unroll
    for (int u = 0; u < 4; ++u)
        hr[t + u * 256] = (bf16)((v[u] - mean) * rstd);
}

// ------- out = LN(x2a+x2b+b2+h) transposed to [b,d,q] -------
__global__ __launch_bounds__(256) void ln_final_k(
    const bf16* __restrict__ Hb,
    const float* __restrict__ X2a, const float* __restrict__ X2b,
    const float* __restrict__ b2,
    float* __restrict__ O)
{
    int row = blockIdx.x, t = threadIdx.x;
    int b = row >> 8, qq = row & 255;
    __shared__ float r1[256], r2[256];
    const float* xa = X2a + (long long)row * 1024;
    const float* xb = X2b + (long long)row * 1024;
    const bf16*  hr = Hb  + (long long)row * 1024;

    float y[4], s = 0.f, ss = 0.f;
#pragma unroll
    for (int u = 0; u < 4; ++u) {
        int c = t + u * 256;
        y[u] = xa[c] + xb[c] + b2[c] + (float)hr[c];
        s += y[u]; ss += y[u] * y[u];
    }
    r1[t] = s; r2[t] = ss;
    __syncthreads();
    for (int off = 128; off > 0; off >>= 1) {
        if (t < off) { r1[t] += r1[t + off]; r2[t] += r2[t + off]; }
        __syncthreads();
    }
    float mean = r1[0] * (1.f / 1024.f);
    float var  = r2[0] * (1.f / 1024.f) - mean * mean;
    float rstd = rsqrtf(var + 1e-5f);

    float* ob = O + (long long)b * 1024 * 256 + qq;
#pragma unroll
    for (int u = 0; u < 4; ++u)
        ob[(long long)(t + u * 256) * 256] = (y[u] - mean) * rstd;
}

extern "C" void kernel_launch(void* const* d_in, const int* in_sizes, int n_in,
                              void* d_out, int out_size, void* d_ws, size_t ws_size,
                              hipStream_t stream) {
    const float* z1ss    = (const float*)d_in[0];   // [16,1024,256]
    const float* uss     = (const float*)d_in[1];   // [16,3072,512]
    const float* mems    = (const float*)d_in[2];   // [16,1024,256]
    const float* pos_emb = (const float*)d_in[3];   // [1024,512]
    const float* Wqkv    = (const float*)d_in[4];   // [3072,1024]
    const float* Wr      = (const float*)d_in[5];   // [1024,1024]
    const float* Wo      = (const float*)d_in[6];   // [1024,1024]
    const float* bo      = (const float*)d_in[7];   // [1024]
    const float* rwb     = (const float*)d_in[8];   // [16,64]
    const float* rrb     = (const float*)d_in[9];   // [16,64]
    const float* W1      = (const float*)d_in[10];  // [4096,1024]
    const float* b1      = (const float*)d_in[11];  // [4096]
    const float* W2      = (const float*)d_in[12];  // [1024,4096]
    const float* b2      = (const float*)d_in[13];  // [1024]

    char* base = (char*)d_ws;
    // Workspace map (bytes), total 138,412,032 (132 MB). Timeline aliases:
    //   x1a/x1b overlay kTB/vBB (Wo writes after attention reads k/v)
    //   ff_b overlays kTB+vBB   (FF1 writes after ln_bf16 consumed x1a/b)
    //   x2a/x2b overlay ussQ/ussK/ussV-head (uss* dead after qkv GEMMs)
    //   hB overlays ussV tail   (ussV dead after v GEMM; ln_bf16 runs later)
    bf16*  catT  = (bf16*) (base + 0);               // [16,512,1024]  alive thru ln_bf16
    bf16*  posT  = (bf16*) (base + 16777216);        // [512,1024]
    bf16*  WqkvB = (bf16*) (base + 17825792);        // [3072,1024]
    bf16*  WrB   = (bf16*) (base + 24117248);        // [1024,1024]
    bf16*  WoB   = (bf16*) (base + 26214400);        // [1024,1024]
    bf16*  W1B   = (bf16*) (base + 28311552);        // [4096,1024]
    bf16*  W2B   = (bf16*) (base + 36700160);        // [1024,4096]
    bf16*  qTB   = (bf16*) (base + 45088768);        // [16,256,1024]
    bf16*  kTB   = (bf16*) (base + 53477376);        // [16,512,1024]
    bf16*  vBB   = (bf16*) (base + 70254592);        // [16,1024,512]
    float* x1a   = (float*)(base + 53477376);        // [4096,1024] overlays kTB
    float* x1b   = (float*)(base + 70254592);        // [4096,1024] overlays vBB
    bf16*  ff_b  = (bf16*) (base + 53477376);        // [4096,4096] overlays kTB+vBB
    bf16*  rhkTB = (bf16*) (base + 87031808);        // [512,1024]
    bf16*  avTB  = (bf16*) (base + 88080384);        // [4096,1024]
    bf16*  ussQb = (bf16*) (base + 96468992);        // [16,256,1024]
    bf16*  ussKb = (bf16*) (base + 104857600);       // [16,512,1024]
    bf16*  ussVb = (bf16*) (base + 121634816);       // [16,1024,512]
    float* x2a   = (float*)(base + 96468992);        // [4096,1024] overlays ussQ+
    float* x2b   = (float*)(base + 113246208);       // [4096,1024] overlays ussK/V
    bf16*  hB    = (bf16*) (base + 130023424);       // [4096,1024] overlays ussV tail

    // ---- prep: straight casts (weights + ussV) ----
    prep_flat_k<<<21504, 256, 0, stream>>>(
        Wqkv, Wr, Wo, W1, W2, uss, WqkvB, WrB, WoB, W1B, W2B, ussVb);

    // ---- prep: all transposes (catT, posT, ussQ, ussK) ----
    prep_tr_k<<<20992, 256, 0, stream>>>(
        mems, z1ss, pos_emb, uss, catT, posT, ussQb, ussKb);

    // ---- merged qk GEMM (+uss bf16 epilogues) + rhk at bz==16 ----
    gemm_bf16<<<dim3(16, 4, 17), 256, 0, stream>>>(
        catT, 512LL * 1024, WqkvB, 0,
        512, 2048, 1024, 0,
        nullptr, nullptr, 0, 0,
        nullptr, 0, qTB, 0,
        1, kTB, ussQb, ussKb, posT, WrB, rhkTB);

    // ---- vB[b,dg,j] = Wqkv[2048:3072] @ catT^T + ussV ----
    gemm_bf16<<<dim3(4, 8, BSZ), 256, 0, stream>>>(
        WqkvB + 2048 * 1024, 0, catT, 512LL * 1024,
        1024, 512, 1024, 0,
        nullptr, ussVb, 1024LL * 512, 0,
        nullptr, 0, vBB, 1024LL * 512,
        0, nullptr, nullptr, nullptr, nullptr, nullptr, nullptr);

    // ---- MFMA banded attention -> avT bf16 [bq, nd] ----
    attn_mfma_k<<<dim3(4, NHEAD, BSZ), 256, 0, stream>>>(
        qTB, kTB, vBB, rhkTB, rwb, rrb, avTB);

    // ---- x1 partials = avT @ Wo^T (split-K=2; bias+residual in ln_bf16) ----
    gemm_bf16<<<dim3(8, 32, 2), 256, 0, stream>>>(
        avTB, 0, WoB, 0,
        4096, 1024, 1024, 512,
        nullptr, nullptr, 0, 0,
        x1a, (long long)(x1b - x1a), nullptr, 0,
        0, nullptr, nullptr, nullptr, nullptr, nullptr, nullptr);

    // ---- h = LN(x1a+x1b+bo+z1ssT) -> bf16 ----
    ln_bf16_k<<<4096, 256, 0, stream>>>(x1a, x1b, bo, catT, hB);

    // ---- ff = relu(h @ W1^T + b1) -> bf16 ----
    gemm_bf16<<<dim3(32, 32, 1), 256, 0, stream>>>(
        hB, 0, W1B, 0,
        4096, 4096, 1024, 0,
        b1, nullptr, 0, 1,
        nullptr, 0, ff_b, 0,
        0, nullptr, nullptr, nullptr, nullptr, nullptr, nullptr);

    // ---- x2 partials = ff @ W2^T (split-K=2; bias+residual in ln_final) ----
    gemm_bf16<<<dim3(8, 32, 2), 256, 0, stream>>>(
        ff_b, 0, W2B, 0,
        4096, 1024, 4096, 2048,
        nullptr, nullptr, 0, 0,
        x2a, (long long)(x2b - x2a), nullptr, 0,
        0, nullptr, nullptr, nullptr, nullptr, nullptr, nullptr);

    // ---- out = LN(x2a+x2b+b2+h) transposed to [b,d,q] ----
    ln_final_k<<<4096, 256, 0, stream>>>(hB, x2a, x2b, b2, (float*)d_out);
}

// Round 6
// 600.132 us; speedup vs baseline: 4.2455x; 1.1376x over previous
//
#include <hip/hip_runtime.h>
#include <hip/hip_bf16.h>
#include <math.h>

// Problem dims (fixed by setup_inputs)
#define BSZ    16
#define DMODEL 1024
#define QLEN   256
#define MLEN   256
#define KLEN   512
#define NHEAD  16
#define DHEAD  64
#define DINNER 4096

typedef __bf16 bf16;
typedef bf16 bf16x8 __attribute__((ext_vector_type(8)));
typedef float f32x4 __attribute__((ext_vector_type(4)));

#define GLOBAL_AS __attribute__((address_space(1)))
#define LDS_AS    __attribute__((address_space(3)))

// ================= prep: all casts + all transposes, one launch =================
// Blocks [0,21504): flat fp32->bf16 casts (5 weights + ussV), 256 float4/block.
// Blocks [21504,42496): 32x32 transpose-casts (catT, posT, ussQ, ussK).
__global__ __launch_bounds__(256) void prep_k(
    const float* __restrict__ Wqkv, const float* __restrict__ Wr,
    const float* __restrict__ Wo,   const float* __restrict__ W1,
    const float* __restrict__ W2,   const float* __restrict__ uss,
    const float* __restrict__ mems, const float* __restrict__ z1ss,
    const float* __restrict__ pos_emb,
    bf16* __restrict__ WqkvB, bf16* __restrict__ WrB, bf16* __restrict__ WoB,
    bf16* __restrict__ W1B,   bf16* __restrict__ W2B, bf16* __restrict__ ussV,
    bf16* __restrict__ catT,  bf16* __restrict__ posT,
    bf16* __restrict__ ussQ,  bf16* __restrict__ ussK)
{
    if (blockIdx.x < 21504) {
        long long i = (long long)blockIdx.x * 256 + threadIdx.x;
        const float* src; bf16* dst; long long soff, doff;
        if      (i <  786432) { src = Wqkv; dst = WqkvB; soff = doff = i; }
        else if (i < 1048576) { src = Wr;   dst = WrB;   soff = doff = i -  786432; }
        else if (i < 1310720) { src = Wo;   dst = WoB;   soff = doff = i - 1048576; }
        else if (i < 2359296) { src = W1;   dst = W1B;   soff = doff = i - 1310720; }
        else if (i < 3407872) { src = W2;   dst = W2B;   soff = doff = i - 2359296; }
        else {
            long long u = i - 3407872, b = u >> 17, r = u & 131071;
            src = uss; dst = ussV; soff = b * 393216 + 262144 + r; doff = u;
        }
        float4 v = ((const float4*)src)[soff];
        bf16 b0 = (bf16)v.x, b1 = (bf16)v.y, b2 = (bf16)v.z, b3 = (bf16)v.w;
        union { ushort u[4]; uint2 d; } p;
        p.u[0] = *(ushort*)&b0; p.u[1] = *(ushort*)&b1;
        p.u[2] = *(ushort*)&b2; p.u[3] = *(ushort*)&b3;
        ((uint2*)dst)[doff] = p.d;
        return;
    }
    __shared__ float tile[32][33];
    int blk = blockIdx.x - 21504;
    const float* src; bf16* dst; long long soff, dof; int ld, ldo, tr, tc;
    if (blk < 8192) {            // catT: (b,half) src [1024,256] -> dst rows 256
        int bh = blk >> 8, t = blk & 255;
        int b = bh >> 1, half = bh & 1;
        tr = t >> 3; tc = t & 7;
        src = half ? z1ss : mems; soff = (long long)b * 1024 * 256; ld = 256;
        dst = catT; dof = ((long long)b * 512 + half * 256) * 1024; ldo = 1024;
    } else if (blk < 8704) {     // posT: [1024,512] -> [512,1024]
        int u = blk - 8192; tr = u >> 4; tc = u & 15;
        src = pos_emb; soff = 0; ld = 512;
        dst = posT; dof = 0; ldo = 1024;
    } else if (blk < 12800) {    // ussQ: uss[b, n<1024, 256+i] -> [b,i,n]
        int u = blk - 8704; int b = u >> 8, t = u & 255;
        tr = t >> 3; tc = t & 7;
        src = uss; soff = (long long)b * 3072 * 512 + 256; ld = 512;
        dst = ussQ; dof = (long long)b * 256 * 1024; ldo = 1024;
    } else {                     // ussK: uss[b, 1024+n, j] -> [b,j,n]
        int u = blk - 12800; int b = u >> 9, t = u & 511;
        tr = t >> 4; tc = t & 15;
        src = uss; soff = ((long long)b * 3072 + 1024) * 512; ld = 512;
        dst = ussK; dof = (long long)b * 512 * 1024; ldo = 1024;
    }
    int tx = threadIdx.x & 31, ty = threadIdx.x >> 5;
    const float* ip = src + soff;
#pragma unroll
    for (int yy = ty; yy < 32; yy += 8)
        tile[yy][tx] = ip[(long long)(tr * 32 + yy) * ld + tc * 32 + tx];
    __syncthreads();
#pragma unroll
    for (int yy = ty; yy < 32; yy += 8)
        dst[dof + (long long)(tc * 32 + yy) * ldo + tr * 32 + tx] = (bf16)tile[tx][yy];
}

// ============== merged qkv+rhk MFMA GEMM, flat grid of 1312 blocks ==============
// All tasks: C[128,128] tile of A[M,1024] x B[N,1024]^T, lead dims 1024.
//   id [0,768):    qk  per-batch: A=catT[b], B=WqkvB; live tiles only
//   id [768,800):  rhk: A=posT, B=WrB -> rhkT
//   id [800,1312): v   per-batch: A=WqkvB+2048*1024 (Wv), B=catT[b] -> vB
// BK=64 as two BK=32 half-stages per barrier pair.
__global__ __launch_bounds__(256) void qkv_gemm_k(
    const bf16* __restrict__ catT, const bf16* __restrict__ WqkvB,
    const bf16* __restrict__ posT, const bf16* __restrict__ WrB,
    const bf16* __restrict__ ussQ, const bf16* __restrict__ ussK,
    const bf16* __restrict__ ussV,
    bf16* __restrict__ qT, bf16* __restrict__ kT,
    bf16* __restrict__ rhkT, bf16* __restrict__ vB)
{
    __shared__ bf16 lA[2 * 128 * 32];
    __shared__ bf16 lB[2 * 128 * 32];

    int id = blockIdx.x;
    int t = threadIdx.x;
    int w = t >> 6, lane = t & 63;

    const bf16 *Ap, *Bp;
    int mode, bz = 0, m0, n0;
    if (id < 768) {
        bz = id / 48; int r = id % 48;
        if (r < 32) { m0 = 256 + ((r >> 4) << 7); n0 = (r & 15) << 7; }
        else        { int rr = r - 32; m0 = (rr >> 3) << 7; n0 = (8 + (rr & 7)) << 7; }
        Ap = catT + (long long)bz * 512 * 1024; Bp = WqkvB; mode = 0;
    } else if (id < 800) {
        int rr = id - 768; m0 = (rr >> 3) << 7; n0 = (rr & 7) << 7;
        Ap = posT; Bp = WrB; mode = 1;
    } else {
        int rr = id - 800; bz = rr >> 5; int tt = rr & 31;
        m0 = (tt >> 2) << 7; n0 = (tt & 3) << 7;
        Ap = WqkvB + 2048 * 1024; Bp = catT + (long long)bz * 512 * 1024; mode = 2;
    }

    int q = lane >> 4, r16 = lane & 15;
    int wm = w >> 1, wn = w & 1;

    f32x4 acc[4][4];
#pragma unroll
    for (int i = 0; i < 4; ++i)
#pragma unroll
        for (int j = 0; j < 4; ++j)
            acc[i][j] = (f32x4){0.f, 0.f, 0.f, 0.f};

    int srow = lane >> 2;
    int scol = (lane & 3) * 8;

    for (int k0 = 0; k0 < 1024; k0 += 64) {
        __syncthreads();
#pragma unroll
        for (int half = 0; half < 2; ++half) {
#pragma unroll
            for (int issue = 0; issue < 2; ++issue) {
                int c = issue * 4 + w;
                int row = c * 16 + srow;
                int col = k0 + half * 32 + scol;
                __builtin_amdgcn_global_load_lds(
                    (const GLOBAL_AS void*)(Ap + (long long)(m0 + row) * 1024 + col),
                    (LDS_AS void*)(lA + half * 4096 + c * 512 + lane * 8), 16, 0, 0);
                __builtin_amdgcn_global_load_lds(
                    (const GLOBAL_AS void*)(Bp + (long long)(n0 + row) * 1024 + col),
                    (LDS_AS void*)(lB + half * 4096 + c * 512 + lane * 8), 16, 0, 0);
            }
        }
        __syncthreads();
#pragma unroll
        for (int kh = 0; kh < 2; ++kh) {
            bf16x8 af[4], bfr[4];
#pragma unroll
            for (int i = 0; i < 4; ++i)
                af[i] = *(const bf16x8*)&lA[kh * 4096 + (wm * 64 + i * 16 + r16) * 32 + q * 8];
#pragma unroll
            for (int j = 0; j < 4; ++j)
                bfr[j] = *(const bf16x8*)&lB[kh * 4096 + (wn * 64 + j * 16 + r16) * 32 + q * 8];
#pragma unroll
            for (int i = 0; i < 4; ++i)
#pragma unroll
                for (int j = 0; j < 4; ++j)
                    acc[i][j] = __builtin_amdgcn_mfma_f32_16x16x32_bf16(
                        af[i], bfr[j], acc[i][j], 0, 0, 0);
        }
    }

    bool isq = (mode == 0) && (n0 < 1024);
#pragma unroll
    for (int i = 0; i < 4; ++i) {
#pragma unroll
        for (int r = 0; r < 4; ++r) {
            int m = m0 + wm * 64 + i * 16 + q * 4 + r;
#pragma unroll
            for (int j = 0; j < 4; ++j) {
                int n = n0 + wn * 64 + j * 16 + r16;
                float v = acc[i][j][r];
                if (mode == 1) {
                    rhkT[(long long)m * 1024 + n] = (bf16)v;
                } else if (mode == 2) {
                    long long idx = ((long long)bz * 1024 + m) * 512 + n;
                    vB[idx] = (bf16)(v + (float)ussV[idx]);
                } else if (isq) {
                    long long idx = ((long long)(bz * 256 + m - 256) << 10) + n;
                    qT[idx] = (bf16)(v + (float)ussQ[idx]);
                } else {
                    long long idx = ((long long)(bz * 512 + m) << 10) + (n - 1024);
                    kT[idx] = (bf16)(v + (float)ussK[idx]);
                }
            }
        }
    }
}

// ---------------- bf16 MFMA GEMM: C[M,N] = A[M,K] * B[N,K]^T ----------------
// 128x128 tile, BK=64 (two BK=32 half-stages per barrier pair), 4 waves.
// kChunk>0: blockIdx.z = K-chunk (split-K; partials to outF + bz*ofBatch).
__global__ __launch_bounds__(256) void gemm_bf16(
    const bf16* __restrict__ A, const bf16* __restrict__ B,
    int M, int N, int K, int kChunk,
    const float* __restrict__ bias, int relu,
    float* __restrict__ outF, long long ofBatch,
    bf16* __restrict__ outB)
{
    __shared__ bf16 lA[2 * 128 * 32];
    __shared__ bf16 lB[2 * 128 * 32];

    int t = threadIdx.x;
    int w = t >> 6, lane = t & 63;
    int m0 = blockIdx.y * 128, n0 = blockIdx.x * 128;
    int bz = blockIdx.z;

    const bf16* Ap = A;
    const bf16* Bp = B;
    float* oF = outF;
    int Keff = K;
    if (kChunk > 0) {
        Ap = A + (long long)bz * kChunk;
        Bp = B + (long long)bz * kChunk;
        if (outF) oF = outF + (long long)bz * ofBatch;
        Keff = kChunk;
    }

    int q = lane >> 4, r16 = lane & 15;
    int wm = w >> 1, wn = w & 1;

    f32x4 acc[4][4];
#pragma unroll
    for (int i = 0; i < 4; ++i)
#pragma unroll
        for (int j = 0; j < 4; ++j)
            acc[i][j] = (f32x4){0.f, 0.f, 0.f, 0.f};

    int srow = lane >> 2;
    int scol = (lane & 3) * 8;

    for (int k0 = 0; k0 < Keff; k0 += 64) {
        __syncthreads();
#pragma unroll
        for (int half = 0; half < 2; ++half) {
#pragma unroll
            for (int issue = 0; issue < 2; ++issue) {
                int c = issue * 4 + w;
                int row = c * 16 + srow;
                int col = k0 + half * 32 + scol;
                __builtin_amdgcn_global_load_lds(
                    (const GLOBAL_AS void*)(Ap + (long long)(m0 + row) * K + col),
                    (LDS_AS void*)(lA + half * 4096 + c * 512 + lane * 8), 16, 0, 0);
                __builtin_amdgcn_global_load_lds(
                    (const GLOBAL_AS void*)(Bp + (long long)(n0 + row) * K + col),
                    (LDS_AS void*)(lB + half * 4096 + c * 512 + lane * 8), 16, 0, 0);
            }
        }
        __syncthreads();
#pragma unroll
        for (int kh = 0; kh < 2; ++kh) {
            bf16x8 af[4], bfr[4];
#pragma unroll
            for (int i = 0; i < 4; ++i)
                af[i] = *(const bf16x8*)&lA[kh * 4096 + (wm * 64 + i * 16 + r16) * 32 + q * 8];
#pragma unroll
            for (int j = 0; j < 4; ++j)
                bfr[j] = *(const bf16x8*)&lB[kh * 4096 + (wn * 64 + j * 16 + r16) * 32 + q * 8];
#pragma unroll
            for (int i = 0; i < 4; ++i)
#pragma unroll
                for (int j = 0; j < 4; ++j)
                    acc[i][j] = __builtin_amdgcn_mfma_f32_16x16x32_bf16(
                        af[i], bfr[j], acc[i][j], 0, 0, 0);
        }
    }

#pragma unroll
    for (int i = 0; i < 4; ++i) {
#pragma unroll
        for (int r = 0; r < 4; ++r) {
            int m = m0 + wm * 64 + i * 16 + q * 4 + r;
#pragma unroll
            for (int j = 0; j < 4; ++j) {
                int n = n0 + wn * 64 + j * 16 + r16;
                float v = acc[i][j][r];
                if (bias) v += bias[n];
                if (relu) v = fmaxf(v, 0.f);
                if (oF)   oF[(long long)m * N + n] = v;
                if (outB) outB[(long long)m * N + n] = (bf16)v;
            }
        }
    }
}

// ---------------- MFMA banded-window rel-pos attention ----------------
__global__ __launch_bounds__(256) void attn_mfma_k(
    const bf16* __restrict__ qT,    // [b,256,1024]
    const bf16* __restrict__ kT,    // [b,512,1024]
    const bf16* __restrict__ vB,    // [b,1024,512]
    const bf16* __restrict__ rhkT,  // [512,1024]
    const float* __restrict__ rwb,  // [16,64]
    const float* __restrict__ rrb,  // [16,64]
    bf16* __restrict__ avT)         // [(b*256+i)*1024 + n*64+d]
{
    __shared__ float sBD[64][132];

    int t = threadIdx.x;
    int w = t >> 6, lane = t & 63;
    int lo = lane & 15, hi = lane >> 4;
    int i0 = blockIdx.x * 64;
    int n  = blockIdx.y;
    int b  = blockIdx.z;

    const bf16* qp = qT + ((long long)(b * 256 + i0 + 16 * w + lo)) * 1024 + n * 64;
    bf16x8 qw[2], qr[2];
#pragma unroll
    for (int ks = 0; ks < 2; ++ks) {
        bf16x8 qv = *(const bf16x8*)(qp + ks * 32 + hi * 8);
        const float* wb = rwb + n * 64 + ks * 32 + hi * 8;
        const float* rb = rrb + n * 64 + ks * 32 + hi * 8;
#pragma unroll
        for (int e = 0; e < 8; ++e) {
            float qf = (float)qv[e];
            qw[ks][e] = (bf16)(qf + wb[e]);
            qr[ks][e] = (bf16)(qf + rb[e]);
        }
    }

    const bf16* rp = rhkT + (long long)384 * 1024 + n * 64;
#pragma unroll
    for (int tj = 0; tj < 8; ++tj) {
        const bf16* bp = rp + (long long)(16 * tj + lo) * 1024;
        f32x4 a = (f32x4){0.f, 0.f, 0.f, 0.f};
        a = __builtin_amdgcn_mfma_f32_16x16x32_bf16(qr[0], *(const bf16x8*)(bp + hi * 8), a, 0, 0, 0);
        a = __builtin_amdgcn_mfma_f32_16x16x32_bf16(qr[1], *(const bf16x8*)(bp + 32 + hi * 8), a, 0, 0, 0);
#pragma unroll
        for (int r = 0; r < 4; ++r)
            sBD[16 * w + hi * 4 + r][16 * tj + lo] = a[r];
    }
    __syncthreads();

    f32x4 ac[12];
    const bf16* kp = kT + ((long long)b * 512 + i0 + 129) * 1024 + n * 64;
#pragma unroll
    for (int tj = 0; tj < 12; ++tj) {
        const bf16* bp = kp + (long long)(16 * tj + lo) * 1024;
        f32x4 a = (f32x4){0.f, 0.f, 0.f, 0.f};
        a = __builtin_amdgcn_mfma_f32_16x16x32_bf16(qw[0], *(const bf16x8*)(bp + hi * 8), a, 0, 0, 0);
        a = __builtin_amdgcn_mfma_f32_16x16x32_bf16(qw[1], *(const bf16x8*)(bp + 32 + hi * 8), a, 0, 0, 0);
        ac[tj] = a;
    }

    float p[12][4], rowmax[4], rowsum[4];
#pragma unroll
    for (int r = 0; r < 4; ++r) rowmax[r] = -1e30f;
#pragma unroll
    for (int tj = 0; tj < 12; ++tj) {
#pragma unroll
        for (int r = 0; r < 4; ++r) {
            int m = 16 * w + hi * 4 + r;
            int jj = 16 * tj + lo;
            int tt = jj - m;
            float v = (tt >= 0 && tt < 128) ? (ac[tj][r] + sBD[m][tt]) * 0.125f
                                            : -1e30f;
            p[tj][r] = v;
            rowmax[r] = fmaxf(rowmax[r], v);
        }
    }
#pragma unroll
    for (int r = 0; r < 4; ++r) {
        float mx = rowmax[r];
#pragma unroll
        for (int msk = 1; msk < 16; msk <<= 1)
            mx = fmaxf(mx, __shfl_xor(mx, msk, 64));
        rowmax[r] = mx;
        rowsum[r] = 0.f;
    }
#pragma unroll
    for (int tj = 0; tj < 12; ++tj) {
#pragma unroll
        for (int r = 0; r < 4; ++r) {
            float e = exp2f((p[tj][r] - rowmax[r]) * 1.44269504f);
            p[tj][r] = e;
            rowsum[r] += e;
        }
    }
#pragma unroll
    for (int r = 0; r < 4; ++r) {
        float s = rowsum[r];
#pragma unroll
        for (int msk = 1; msk < 16; msk <<= 1)
            s += __shfl_xor(s, msk, 64);
        rowsum[r] = 1.f / s;
    }

    bf16* P = (bf16*)&sBD[0][0];
#pragma unroll
    for (int tj = 0; tj < 12; ++tj) {
#pragma unroll
        for (int r = 0; r < 4; ++r) {
            int m = 16 * w + hi * 4 + r;
            P[m * 264 + 16 * tj + lo] = (bf16)(p[tj][r] * rowsum[r]);
        }
    }
    __syncthreads();

    f32x4 oacc[4];
#pragma unroll
    for (int td = 0; td < 4; ++td) oacc[td] = (f32x4){0.f, 0.f, 0.f, 0.f};
    const bf16* vp = vB + ((long long)b * 1024 + n * 64) * 512 + i0 + 129;
#pragma unroll
    for (int ks = 0; ks < 6; ++ks) {
        bf16x8 af = *(const bf16x8*)(P + (16 * w + lo) * 264 + ks * 32 + hi * 8);
#pragma unroll
        for (int td = 0; td < 4; ++td) {
            bf16x8 bv = *(const bf16x8*)(vp + (long long)(16 * td + lo) * 512 + ks * 32 + hi * 8);
            oacc[td] = __builtin_amdgcn_mfma_f32_16x16x32_bf16(af, bv, oacc[td], 0, 0, 0);
        }
    }
    bf16* op = avT + ((long long)(b * 256 + i0 + 16 * w)) * 1024 + n * 64;
#pragma unroll
    for (int td = 0; td < 4; ++td)
#pragma unroll
        for (int r = 0; r < 4; ++r)
            op[(long long)(hi * 4 + r) * 1024 + 16 * td + lo] = (bf16)oacc[td][r];
}

// ------- h = LN(x1a+x1b+bo+z1ssT) -> bf16;  rows of [4096,1024] -------
__global__ __launch_bounds__(256) void ln_bf16_k(
    const float* __restrict__ X1a, const float* __restrict__ X1b,
    const float* __restrict__ bo,  const bf16* __restrict__ catT,
    bf16* __restrict__ H)
{
    int row = blockIdx.x, t = threadIdx.x;
    __shared__ float r1[256], r2[256];
    const float* xa = X1a + (long long)row * 1024;
    const float* xb = X1b + (long long)row * 1024;
    const bf16*  zr = catT + ((long long)(row >> 8) * 512 + 256 + (row & 255)) * 1024;
    float v[4], s = 0.f, ss = 0.f;
#pragma unroll
    for (int u = 0; u < 4; ++u) {
        int c = t + u * 256;
        v[u] = xa[c] + xb[c] + bo[c] + (float)zr[c];
        s += v[u]; ss += v[u] * v[u];
    }
    r1[t] = s; r2[t] = ss;
    __syncthreads();
    for (int off = 128; off > 0; off >>= 1) {
        if (t < off) { r1[t] += r1[t + off]; r2[t] += r2[t + off]; }
        __syncthreads();
    }
    float mean = r1[0] * (1.f / 1024.f);
    float var  = r2[0] * (1.f / 1024.f) - mean * mean;
    float rstd = rsqrtf(var + 1e-5f);
    bf16* hr = H + (long long)row * 1024;
#pragma unroll
    for (int u = 0; u < 4; ++u)
        hr[t + u * 256] = (bf16)((v[u] - mean) * rstd);
}

// ------- out = LN(x2a+x2b+b2+h) transposed to [b,d,q] -------
__global__ __launch_bounds__(256) void ln_final_k(
    const bf16* __restrict__ Hb,
    const float* __restrict__ X2a, const float* __restrict__ X2b,
    const float* __restrict__ b2,
    float* __restrict__ O)
{
    int row = blockIdx.x, t = threadIdx.x;
    int b = row >> 8, qq = row & 255;
    __shared__ float r1[256], r2[256];
    const float* xa = X2a + (long long)row * 1024;
    const float* xb = X2b + (long long)row * 1024;
    const bf16*  hr = Hb  + (long long)row * 1024;

    float y[4], s = 0.f, ss = 0.f;
#pragma unroll
    for (int u = 0; u < 4; ++u) {
        int c = t + u * 256;
        y[u] = xa[c] + xb[c] + b2[c] + (float)hr[c];
        s += y[u]; ss += y[u] * y[u];
    }
    r1[t] = s; r2[t] = ss;
    __syncthreads();
    for (int off = 128; off > 0; off >>= 1) {
        if (t < off) { r1[t] += r1[t + off]; r2[t] += r2[t + off]; }
        __syncthreads();
    }
    float mean = r1[0] * (1.f / 1024.f);
    float var  = r2[0] * (1.f / 1024.f) - mean * mean;
    float rstd = rsqrtf(var + 1e-5f);

    float* ob = O + (long long)b * 1024 * 256 + qq;
#pragma unroll
    for (int u = 0; u < 4; ++u)
        ob[(long long)(t + u * 256) * 256] = (y[u] - mean) * rstd;
}

extern "C" void kernel_launch(void* const* d_in, const int* in_sizes, int n_in,
                              void* d_out, int out_size, void* d_ws, size_t ws_size,
                              hipStream_t stream) {
    const float* z1ss    = (const float*)d_in[0];   // [16,1024,256]
    const float* uss     = (const float*)d_in[1];   // [16,3072,512]
    const float* mems    = (const float*)d_in[2];   // [16,1024,256]
    const float* pos_emb = (const float*)d_in[3];   // [1024,512]
    const float* Wqkv    = (const float*)d_in[4];   // [3072,1024]
    const float* Wr      = (const float*)d_in[5];   // [1024,1024]
    const float* Wo      = (const float*)d_in[6];   // [1024,1024]
    const float* bo      = (const float*)d_in[7];   // [1024]
    const float* rwb     = (const float*)d_in[8];   // [16,64]
    const float* rrb     = (const float*)d_in[9];   // [16,64]
    const float* W1      = (const float*)d_in[10];  // [4096,1024]
    const float* b1      = (const float*)d_in[11];  // [4096]
    const float* W2      = (const float*)d_in[12];  // [1024,4096]
    const float* b2      = (const float*)d_in[13];  // [1024]

    char* base = (char*)d_ws;
    // Workspace map (bytes), total 138,412,032 (132 MB). Timeline aliases:
    //   x1a/x1b overlay kTB/vBB (Wo writes after attention reads k/v)
    //   ff_b overlays kTB+vBB   (FF1 writes after ln_bf16 consumed x1a/b)
    //   x2a/x2b overlay ussQ/ussK/ussV-head (uss* dead after qkv GEMMs)
    //   hB overlays ussV tail   (ussV dead after qkv GEMM; ln_bf16 runs later)
    bf16*  catT  = (bf16*) (base + 0);               // [16,512,1024]  alive thru ln_bf16
    bf16*  posT  = (bf16*) (base + 16777216);        // [512,1024]
    bf16*  WqkvB = (bf16*) (base + 17825792);        // [3072,1024]
    bf16*  WrB   = (bf16*) (base + 24117248);        // [1024,1024]
    bf16*  WoB   = (bf16*) (base + 26214400);        // [1024,1024]
    bf16*  W1B   = (bf16*) (base + 28311552);        // [4096,1024]
    bf16*  W2B   = (bf16*) (base + 36700160);        // [1024,4096]
    bf16*  qTB   = (bf16*) (base + 45088768);        // [16,256,1024]
    bf16*  kTB   = (bf16*) (base + 53477376);        // [16,512,1024]
    bf16*  vBB   = (bf16*) (base + 70254592);        // [16,1024,512]
    float* x1a   = (float*)(base + 53477376);        // [4096,1024] overlays kTB
    float* x1b   = (float*)(base + 70254592);        // [4096,1024] overlays vBB
    bf16*  ff_b  = (bf16*) (base + 53477376);        // [4096,4096] overlays kTB+vBB
    bf16*  rhkTB = (bf16*) (base + 87031808);        // [512,1024]
    bf16*  avTB  = (bf16*) (base + 88080384);        // [4096,1024]
    bf16*  ussQb = (bf16*) (base + 96468992);        // [16,256,1024]
    bf16*  ussKb = (bf16*) (base + 104857600);       // [16,512,1024]
    bf16*  ussVb = (bf16*) (base + 121634816);       // [16,1024,512]
    float* x2a   = (float*)(base + 96468992);        // [4096,1024] overlays ussQ+
    float* x2b   = (float*)(base + 113246208);       // [4096,1024] overlays ussK/V
    bf16*  hB    = (bf16*) (base + 130023424);       // [4096,1024] overlays ussV tail

    // ---- prep: all casts + transposes, one launch ----
    prep_k<<<42496, 256, 0, stream>>>(
        Wqkv, Wr, Wo, W1, W2, uss, mems, z1ss, pos_emb,
        WqkvB, WrB, WoB, W1B, W2B, ussVb, catT, posT, ussQb, ussKb);

    // ---- merged qkv + rhk GEMM (single dispatch, 1312 blocks) ----
    qkv_gemm_k<<<1312, 256, 0, stream>>>(
        catT, WqkvB, posT, WrB, ussQb, ussKb, ussVb, qTB, kTB, rhkTB, vBB);

    // ---- MFMA banded attention -> avT bf16 [bq, nd] ----
    attn_mfma_k<<<dim3(4, NHEAD, BSZ), 256, 0, stream>>>(
        qTB, kTB, vBB, rhkTB, rwb, rrb, avTB);

    // ---- x1 partials = avT @ Wo^T (split-K=2; bias+residual in ln_bf16) ----
    gemm_bf16<<<dim3(8, 32, 2), 256, 0, stream>>>(
        avTB, WoB, 4096, 1024, 1024, 512,
        nullptr, 0, x1a, (long long)(x1b - x1a), nullptr);

    // ---- h = LN(x1a+x1b+bo+z1ssT) -> bf16 ----
    ln_bf16_k<<<4096, 256, 0, stream>>>(x1a, x1b, bo, catT, hB);

    // ---- ff = relu(h @ W1^T + b1) -> bf16 ----
    gemm_bf16<<<dim3(32, 32, 1), 256, 0, stream>>>(
        hB, W1B, 4096, 4096, 1024, 0,
        b1, 1, nullptr, 0, ff_b);

    // ---- x2 partials = ff @ W2^T (split-K=2; bias+residual in ln_final) ----
    gemm_bf16<<<dim3(8, 32, 2), 256, 0, stream>>>(
        ff_b, W2B, 4096, 1024, 4096, 2048,
        nullptr, 0, x2a, (long long)(x2b - x2a), nullptr);

    // ---- out = LN(x2a+x2b+b2+h) transposed to [b,d,q] ----
    ln_final_k<<<4096, 256, 0, stream>>>(hB, x2a, x2b, b2, (float*)d_out);
}